// Round 9
// baseline (729.486 us; speedup 1.0000x reference)
//
#include <hip/hip_runtime.h>
#include <hip/hip_bf16.h>

#define DEV __device__ __forceinline__

constexpr int B = 16, T = 400, H = 400, V = 22000, S = 30, STEPS = 8, NG = 3;
constexpr int M  = S * B;      // 480
constexpr int H3 = 3 * H;      // 1200
constexpr int KP = 448;        // K padded to 7*64
constexpr int VP = 22016;      // V padded to 172*128
constexpr int MP = 512;        // M padded (per step slot)
constexpr int MR = STEPS * MP; // 4096
constexpr int NWP = 1280;
constexpr int NBLK = VP / 128; // 172
constexpr int NMP = MR / 256;  // 16
constexpr int NVB = NBLK * NMP;// 2752 (8 | NVB)
constexpr int TPAD = 416;
constexpr int PLD = 424;
constexpr long long PTS = (long long)S * B * STEPS * V;

typedef __attribute__((ext_vector_type(8))) short bfrag;
typedef __attribute__((ext_vector_type(4))) float f32x4;
typedef unsigned short u16;

DEV u16 f2bf(float x) {                 // manual RNE (init/split paths)
  unsigned u = __float_as_uint(x);
  u += 0x7FFFu + ((u >> 16) & 1u);
  return (u16)(u >> 16);
}
DEV u16 f2bfn(float x) {                // native cvt (hot paths)
  __hip_bfloat16 h = __float2bfloat16(x);
  union { __hip_bfloat16 b; u16 u; } cv; cv.b = h; return cv.u;
}
DEV float bf2f(u16 h) { return __uint_as_float(((unsigned)h) << 16); }
DEV float sigm(float x) { return 1.0f / (1.0f + __expf(-x)); }

DEV void gload16(const u16* g, u16* l) {
  __builtin_amdgcn_global_load_lds(
      (const __attribute__((address_space(1))) void*)g,
      (__attribute__((address_space(3))) void*)l, 16, 0, 0);
}

// ---------------- merged init ----------------
constexpr int N_EMB = VP * KP / 256;           // 38528
constexpr int N_ENC = B * 400 * TPAD / 256;    // 10400
constexpr int N_W   = NWP * KP / 256;          // 2240
constexpr int N_DEC = STEPS * MP * KP / 256;   // 7168
constexpr int N_H0  = MP * KP / 256;           // 896
constexpr int N_ZP  = STEPS * (MP - M) * KP / 256; // 448
constexpr int N_ZE  = MR * 16 / 256;           // 256
constexpr int N_INIT = N_EMB + N_ENC + N_W + N_DEC + N_H0 + N_ZP + N_ZE;

__global__ __launch_bounds__(256) void k_init(
    const float* __restrict__ emb, const float* __restrict__ enc,
    const float* __restrict__ Wih, const float* __restrict__ Whh,
    const float* __restrict__ semb, const float* __restrict__ ehid,
    const int* __restrict__ tgt,
    u16* __restrict__ ebf, u16* __restrict__ encbK, u16* __restrict__ encT,
    u16* __restrict__ wihH, u16* __restrict__ wihL,
    u16* __restrict__ whhH, u16* __restrict__ whhL,
    float* __restrict__ dec, u16* __restrict__ decH, u16* __restrict__ decL,
    float* __restrict__ h0F, u16* __restrict__ h0H, u16* __restrict__ h0L,
    u16* __restrict__ hAllH, u16* __restrict__ hAllL, u16* __restrict__ ebuf)
{
  int bx = blockIdx.x;
  const int tid = threadIdx.x;
  if (bx < N_EMB) {
    int i = bx * 256 + tid;
    int v = i / KP, k = i % KP;
    ebf[i] = f2bf((v < V && k < H) ? emb[(long long)v * H + k] : 0.f);
    return;
  }
  bx -= N_EMB;
  if (bx < N_ENC) {
    int i = bx * 256 + tid;
    int c = i % TPAD, r = (i / TPAD) % 400, b = i / (TPAD * 400);
    encbK[i] = f2bf((c < H) ? enc[((size_t)b * T + r) * H + c] : 0.f);
    encT[i]  = f2bf((c < T) ? enc[((size_t)b * T + c) * H + r] : 0.f);
    return;
  }
  bx -= N_ENC;
  if (bx < N_W) {
    int i = bx * 256 + tid;
    int n = i / KP, k = i % KP;
    float v1 = (n < H3 && k < H) ? Wih[n * H + k] : 0.f;
    u16 h1 = f2bf(v1);
    wihH[i] = h1; wihL[i] = f2bf(v1 - bf2f(h1));
    float v2 = (n < H3 && k < H) ? Whh[n * H + k] : 0.f;
    u16 h2 = f2bf(v2);
    whhH[i] = h2; whhL[i] = f2bf(v2 - bf2f(h2));
    return;
  }
  bx -= N_W;
  if (bx < N_DEC) {
    int i = bx * 256 + tid;
    int k = i % KP, m = (i / KP) % MP, s = i / (KP * MP);
    float val = 0.f;
    if (m < M && k < H) {
      int slot = m / B, b = m % B;
      if (s == 0) val = semb[slot * H + k];
      else        val = emb[(long long)tgt[(b * S + slot) * STEPS + (s - 1)] * H + k];
      dec[((long long)s * M + m) * H + k] = val;
    }
    u16 hi = f2bf(val);
    decH[i] = hi; decL[i] = f2bf(val - bf2f(hi));
    return;
  }
  bx -= N_DEC;
  if (bx < N_H0) {
    int i = bx * 256 + tid;
    int k = i % KP, m = i / KP;
    float val = (m < M && k < H) ? ehid[(m % B) * H + k] : 0.f;
    if (m < M && k < H) h0F[m * H + k] = val;
    u16 hi = f2bf(val);
    h0H[i] = hi; h0L[i] = f2bf(val - bf2f(hi));
    return;
  }
  bx -= N_H0;
  if (bx < N_ZP) {
    int i = bx * 256 + tid;
    int k = i % KP;
    int row = M + (i / KP) % (MP - M);
    int s = i / (KP * (MP - M));
    size_t idx = ((size_t)s * MP + row) * KP + k;
    hAllH[idx] = 0; hAllL[idx] = 0;
    return;
  }
  bx -= N_ZP;
  {
    int i = bx * 256 + tid;           // MR*16: zero ebuf cols [V,VP)
    int row = i / 16, col = V + (i % 16);
    ebuf[(size_t)row * VP + col] = 0;
  }
}

// ---------------- 64x64-tile SPLIT GEMM (gi batched) ----------------
__global__ __launch_bounds__(256) void k_gemm64s(
    const u16* __restrict__ Ahi, const u16* __restrict__ Alo,
    const u16* __restrict__ Bmh, const u16* __restrict__ Bml,
    const float* __restrict__ bias, float* __restrict__ C,
    int Mvalid, int Nvalid, int Cstride)
{
  __shared__ u16 BsH[64 * 32], BsL[64 * 32];
  const int tid = threadIdx.x;
  const int wave = tid >> 6, lane = tid & 63;
  const int wm = wave >> 1, wn = wave & 1;
  const int n0 = blockIdx.x * 64;
  const int m0 = blockIdx.y * 64;
  const int lrow = lane & 15;
  const int c16 = lane >> 4;
  const int srow = tid >> 2;
  const int sg = (tid & 3) ^ ((srow >> 1) & 3);   // 64B rows: f(r)=(r>>1)&3
  f32x4 acc[2][2] = {};

  const u16* aH = Ahi + (size_t)(m0 + wm * 32 + lrow) * KP + c16 * 8;
  const u16* aL = Alo + (size_t)(m0 + wm * 32 + lrow) * KP + c16 * 8;
  const u16* bHs = Bmh + (size_t)(n0 + srow) * KP + sg * 8;
  const u16* bLs = Bml + (size_t)(n0 + srow) * KP + sg * 8;
  u16* lBH = BsH + wave * 512;
  u16* lBL = BsL + wave * 512;

  for (int kk = 0; kk < KP / 32; ++kk) {
    const int kb = kk * 32;
    gload16(bHs + kb, lBH);
    gload16(bLs + kb, lBL);
    __syncthreads();
    bfrag a0h = *(const bfrag*)(aH + kb);
    bfrag a1h = *(const bfrag*)(aH + 16 * KP + kb);
    bfrag a0l = *(const bfrag*)(aL + kb);
    bfrag a1l = *(const bfrag*)(aL + 16 * KP + kb);
#pragma unroll
    for (int nn = 0; nn < 2; ++nn) {
      const int br = wn * 32 + nn * 16 + lrow;
      const int goff = br * 32 + ((c16 ^ ((br >> 1) & 3)) << 3);
      bfrag bh = *(const bfrag*)&BsH[goff];
      bfrag bl = *(const bfrag*)&BsL[goff];
      acc[0][nn] = __builtin_amdgcn_mfma_f32_16x16x32_bf16(a0h, bh, acc[0][nn], 0, 0, 0);
      acc[1][nn] = __builtin_amdgcn_mfma_f32_16x16x32_bf16(a1h, bh, acc[1][nn], 0, 0, 0);
      acc[0][nn] = __builtin_amdgcn_mfma_f32_16x16x32_bf16(a0h, bl, acc[0][nn], 0, 0, 0);
      acc[1][nn] = __builtin_amdgcn_mfma_f32_16x16x32_bf16(a1h, bl, acc[1][nn], 0, 0, 0);
      acc[0][nn] = __builtin_amdgcn_mfma_f32_16x16x32_bf16(a0l, bh, acc[0][nn], 0, 0, 0);
      acc[1][nn] = __builtin_amdgcn_mfma_f32_16x16x32_bf16(a1l, bh, acc[1][nn], 0, 0, 0);
    }
    __syncthreads();
  }
  const int orow = (lane >> 4) << 2, ocol = lane & 15;
#pragma unroll
  for (int am = 0; am < 2; ++am) {
#pragma unroll
    for (int nn = 0; nn < 2; ++nn) {
      const int gn = n0 + wn * 32 + nn * 16 + ocol;
      if (gn >= Nvalid) continue;
      const float badd = bias[gn];
#pragma unroll
      for (int r = 0; r < 4; ++r) {
        const int gm = m0 + wm * 32 + am * 16 + orow + r;
        if (gm < Mvalid) C[(long long)gm * Cstride + gn] = acc[am][nn][r] + badd;
      }
    }
  }
}

// ---------------- k_grustep: gh GEMM (3 gates) + GRU cell fused ----------------
// block (c0, m0): 64 h-cols x 64 rows, all 3 gates; cell applied in-register.
__global__ __launch_bounds__(256) void k_grustep(
    const u16* __restrict__ hpH, const u16* __restrict__ hpL,
    const float* __restrict__ hprevF,
    const u16* __restrict__ whhH, const u16* __restrict__ whhL,
    const float* __restrict__ bhh, const float* __restrict__ gi_s,
    float* __restrict__ hcurF, u16* __restrict__ hcH, u16* __restrict__ hcL)
{
  __shared__ u16 BsH[3][64 * 32], BsL[3][64 * 32];
  const int tid = threadIdx.x;
  const int wave = tid >> 6, lane = tid & 63;
  const int wm = wave >> 1, wn = wave & 1;
  const int c0 = blockIdx.x * 64;     // h-col window
  const int m0 = blockIdx.y * 64;
  const int lrow = lane & 15;
  const int c16 = lane >> 4;
  const int srow = tid >> 2;
  const int sg = (tid & 3) ^ ((srow >> 1) & 3);
  f32x4 acc[3][2][2] = {};

  const u16* aH = hpH + (size_t)(m0 + wm * 32 + lrow) * KP + c16 * 8;
  const u16* aL = hpL + (size_t)(m0 + wm * 32 + lrow) * KP + c16 * 8;
  const u16* bH0 = whhH + (size_t)(c0 + srow) * KP + sg * 8;
  const u16* bL0 = whhL + (size_t)(c0 + srow) * KP + sg * 8;

  for (int kk = 0; kk < KP / 32; ++kk) {
    const int kb = kk * 32;
#pragma unroll
    for (int g = 0; g < 3; ++g) {
      gload16(bH0 + (size_t)g * 400 * KP + kb, &BsH[g][wave * 512]);
      gload16(bL0 + (size_t)g * 400 * KP + kb, &BsL[g][wave * 512]);
    }
    __syncthreads();
    bfrag a0h = *(const bfrag*)(aH + kb);
    bfrag a1h = *(const bfrag*)(aH + 16 * KP + kb);
    bfrag a0l = *(const bfrag*)(aL + kb);
    bfrag a1l = *(const bfrag*)(aL + 16 * KP + kb);
#pragma unroll
    for (int g = 0; g < 3; ++g) {
#pragma unroll
      for (int nn = 0; nn < 2; ++nn) {
        const int br = wn * 32 + nn * 16 + lrow;
        const int goff = br * 32 + ((c16 ^ ((br >> 1) & 3)) << 3);
        bfrag bh = *(const bfrag*)&BsH[g][goff];
        bfrag bl = *(const bfrag*)&BsL[g][goff];
        acc[g][0][nn] = __builtin_amdgcn_mfma_f32_16x16x32_bf16(a0h, bh, acc[g][0][nn], 0, 0, 0);
        acc[g][1][nn] = __builtin_amdgcn_mfma_f32_16x16x32_bf16(a1h, bh, acc[g][1][nn], 0, 0, 0);
        acc[g][0][nn] = __builtin_amdgcn_mfma_f32_16x16x32_bf16(a0h, bl, acc[g][0][nn], 0, 0, 0);
        acc[g][1][nn] = __builtin_amdgcn_mfma_f32_16x16x32_bf16(a1h, bl, acc[g][1][nn], 0, 0, 0);
        acc[g][0][nn] = __builtin_amdgcn_mfma_f32_16x16x32_bf16(a0l, bh, acc[g][0][nn], 0, 0, 0);
        acc[g][1][nn] = __builtin_amdgcn_mfma_f32_16x16x32_bf16(a1l, bh, acc[g][1][nn], 0, 0, 0);
      }
    }
    __syncthreads();
  }
  const int orow = (lane >> 4) << 2, ocol = lane & 15;
#pragma unroll
  for (int am = 0; am < 2; ++am) {
#pragma unroll
    for (int nn = 0; nn < 2; ++nn) {
      const int gk = c0 + wn * 32 + nn * 16 + ocol;
      if (gk >= H) continue;
      const float b0 = bhh[gk], b1 = bhh[H + gk], b2 = bhh[2 * H + gk];
#pragma unroll
      for (int r = 0; r < 4; ++r) {
        const int gm = m0 + wm * 32 + am * 16 + orow + r;
        if (gm >= M) continue;
        float ir = gi_s[(size_t)gm * H3 + gk];
        float iz = gi_s[(size_t)gm * H3 + H + gk];
        float in_ = gi_s[(size_t)gm * H3 + 2 * H + gk];
        float rr = sigm(ir + acc[0][am][nn][r] + b0);
        float z  = sigm(iz + acc[1][am][nn][r] + b1);
        float n  = tanhf(in_ + rr * (acc[2][am][nn][r] + b2));
        float hv = (1.f - z) * n + z * hprevF[(size_t)gm * H + gk];
        hcurF[(size_t)gm * H + gk] = hv;
        u16 hb = f2bf(hv);
        hcH[(size_t)gm * KP + gk] = hb;
        hcL[(size_t)gm * KP + gk] = f2bf(hv - bf2f(hb));
      }
    }
  }
}

// ---------------- k_attn: MFMA attention, one block per (s,b) ----------------
struct SMatt {
  u16 P[32 * PLD];
  float partm[32][4];
  float parts[32][4];
  float rowred[32];
  float part2[32][4][4];
};

__global__ __launch_bounds__(512) void k_attn(
    const u16* __restrict__ hAllH, const u16* __restrict__ hAllL,
    const float* __restrict__ hallF,
    const u16* __restrict__ encbK, const u16* __restrict__ encT,
    const int* __restrict__ lens, const float* __restrict__ dec,
    const float* __restrict__ Wr, const float* __restrict__ br,
    const float* __restrict__ Wg, const float* __restrict__ bg,
    float* __restrict__ attnB, float* __restrict__ pgenB, float* __restrict__ out)
{
  __shared__ SMatt sm;
  const int s = blockIdx.x >> 4;
  const int b = blockIdx.x & 15;
  const int tid = threadIdx.x;
  const int wave = tid >> 6, lane = tid & 63;
  const int mt = wave & 1;
  const int wg = wave >> 1;
  const int lrow = lane & 15;
  const int c16 = lane >> 4;
  const int len = lens[b];
  const int rbase = mt * 16 + c16 * 4;

  for (int idx = tid; idx < 32 * 24; idx += 512)
    sm.P[(idx / 24) * PLD + 400 + (idx % 24)] = 0;

  f32x4 acc[7] = {};
  {
    const size_t arow = (size_t)s * MP + (size_t)(mt * 16 + lrow) * B + b;
    const u16* aHp = hAllH + arow * KP + c16 * 8;
    const u16* aLp = hAllL + arow * KP + c16 * 8;
    const u16* bBase = encbK + (size_t)b * 400 * TPAD + c16 * 8;
    for (int kk = 0; kk < 13; ++kk) {
      bfrag ah = *(const bfrag*)(aHp + kk * 32);
      bfrag al = *(const bfrag*)(aLp + kk * 32);
#pragma unroll
      for (int i = 0; i < 7; ++i) {
        const int jt = wg + 4 * i;
        if (jt < 25) {
          bfrag bv = *(const bfrag*)(bBase + (size_t)(jt * 16 + lrow) * TPAD + kk * 32);
          acc[i] = __builtin_amdgcn_mfma_f32_16x16x32_bf16(ah, bv, acc[i], 0, 0, 0);
          acc[i] = __builtin_amdgcn_mfma_f32_16x16x32_bf16(al, bv, acc[i], 0, 0, 0);
        }
      }
    }
  }

  {
    float pm[4] = {-1e30f, -1e30f, -1e30f, -1e30f};
#pragma unroll
    for (int i = 0; i < 7; ++i) {
      const int jt = wg + 4 * i;
      if (jt >= 25) continue;
      const int t = jt * 16 + lrow;
      const bool ok = t < len;
#pragma unroll
      for (int rr = 0; rr < 4; ++rr) pm[rr] = fmaxf(pm[rr], ok ? acc[i][rr] : -1e30f);
    }
#pragma unroll
    for (int d = 1; d < 16; d <<= 1) {
#pragma unroll
      for (int rr = 0; rr < 4; ++rr) pm[rr] = fmaxf(pm[rr], __shfl_xor(pm[rr], d));
    }
    if (lrow == 0) {
#pragma unroll
      for (int rr = 0; rr < 4; ++rr) sm.partm[rbase + rr][wg] = pm[rr];
    }
  }
  __syncthreads();
  if (tid < 32)
    sm.rowred[tid] = fmaxf(fmaxf(sm.partm[tid][0], sm.partm[tid][1]),
                           fmaxf(sm.partm[tid][2], sm.partm[tid][3]));
  __syncthreads();
  float Mx[4];
#pragma unroll
  for (int rr = 0; rr < 4; ++rr) Mx[rr] = sm.rowred[rbase + rr];
  {
    float ps[4] = {0.f, 0.f, 0.f, 0.f};
#pragma unroll
    for (int i = 0; i < 7; ++i) {
      const int jt = wg + 4 * i;
      if (jt >= 25) continue;
      const int t = jt * 16 + lrow;
      const bool ok = t < len;
#pragma unroll
      for (int rr = 0; rr < 4; ++rr) {
        float e = ok ? __expf(acc[i][rr] - Mx[rr]) : 0.f;
        acc[i][rr] = e;
        ps[rr] += e;
      }
    }
#pragma unroll
    for (int d = 1; d < 16; d <<= 1) {
#pragma unroll
      for (int rr = 0; rr < 4; ++rr) ps[rr] += __shfl_xor(ps[rr], d);
    }
    if (lrow == 0) {
#pragma unroll
      for (int rr = 0; rr < 4; ++rr) sm.parts[rbase + rr][wg] = ps[rr];
    }
  }
  __syncthreads();
  if (tid < 32)
    sm.rowred[tid] = sm.parts[tid][0] + sm.parts[tid][1] + sm.parts[tid][2] + sm.parts[tid][3];
  __syncthreads();
  {
    float inv[4];
#pragma unroll
    for (int rr = 0; rr < 4; ++rr) inv[rr] = 1.f / sm.rowred[rbase + rr];
#pragma unroll
    for (int i = 0; i < 7; ++i) {
      const int jt = wg + 4 * i;
      if (jt >= 25) continue;
      const int t = jt * 16 + lrow;
#pragma unroll
      for (int rr = 0; rr < 4; ++rr) {
        const int row = rbase + rr;
        const float p = acc[i][rr] * inv[rr];
        sm.P[row * PLD + t] = f2bfn(p);
        if (row < 30) attnB[((size_t)s * M + row * B + b) * T + t] = p;
      }
    }
  }
  __syncthreads();

  f32x4 acc2[7] = {};
  {
    const u16* bBase = encT + (size_t)b * 400 * TPAD + c16 * 8;
    const u16* aP = sm.P + (mt * 16 + lrow) * PLD + c16 * 8;
    for (int kk = 0; kk < 13; ++kk) {
      bfrag ap = *(const bfrag*)(aP + kk * 32);
#pragma unroll
      for (int i = 0; i < 7; ++i) {
        const int jk = wg + 4 * i;
        if (jk < 25) {
          bfrag bv = *(const bfrag*)(bBase + (size_t)(jk * 16 + lrow) * TPAD + kk * 32);
          acc2[i] = __builtin_amdgcn_mfma_f32_16x16x32_bf16(ap, bv, acc2[i], 0, 0, 0);
        }
      }
    }
  }
  {
    float pw[4] = {0.f, 0.f, 0.f, 0.f};
    float pg0[4] = {0.f, 0.f, 0.f, 0.f};
    float pg1[4] = {0.f, 0.f, 0.f, 0.f};
    float pg2[4] = {0.f, 0.f, 0.f, 0.f};
    const bool do_g = (s == 0);
#pragma unroll
    for (int i = 0; i < 7; ++i) {
      const int jk = wg + 4 * i;
      if (jk >= 25) continue;
      const int k = jk * 16 + lrow;
      const float wr = Wr[H + k];
      float w0 = 0.f, w1 = 0.f, w2 = 0.f;
      if (do_g) { w0 = Wg[k]; w1 = Wg[H + k]; w2 = Wg[2 * H + k]; }
#pragma unroll
      for (int rr = 0; rr < 4; ++rr) {
        const float v = acc2[i][rr];
        pw[rr] = fmaf(v, wr, pw[rr]);
        if (do_g) {
          pg0[rr] = fmaf(v, w0, pg0[rr]);
          pg1[rr] = fmaf(v, w1, pg1[rr]);
          pg2[rr] = fmaf(v, w2, pg2[rr]);
        }
      }
    }
#pragma unroll
    for (int d = 1; d < 16; d <<= 1) {
#pragma unroll
      for (int rr = 0; rr < 4; ++rr) {
        pw[rr] += __shfl_xor(pw[rr], d);
        pg0[rr] += __shfl_xor(pg0[rr], d);
        pg1[rr] += __shfl_xor(pg1[rr], d);
        pg2[rr] += __shfl_xor(pg2[rr], d);
      }
    }
    if (lrow == 0) {
#pragma unroll
      for (int rr = 0; rr < 4; ++rr) {
        sm.part2[rbase + rr][wg][0] = pw[rr];
        sm.part2[rbase + rr][wg][1] = pg0[rr];
        sm.part2[rbase + rr][wg][2] = pg1[rr];
        sm.part2[rbase + rr][wg][3] = pg2[rr];
      }
    }
  }
  __syncthreads();

  if (tid < 480) {
    const int row = tid >> 4;
    const int l16 = tid & 15;
    const int m = row * B + b;
    const float* hF = hallF + ((size_t)s * M + m) * H;
    const float* dF = dec + ((size_t)s * M + m) * H;
    float p = 0.f;
    for (int j = 0; j < 25; ++j) {
      const int k = l16 + 16 * j;
      p += hF[k] * Wr[k] + dF[k] * Wr[2 * H + k];
    }
#pragma unroll
    for (int d = 1; d < 16; d <<= 1) p += __shfl_xor(p, d);
    if (l16 == 0) {
      float cw = sm.part2[row][0][0] + sm.part2[row][1][0] +
                 sm.part2[row][2][0] + sm.part2[row][3][0];
      pgenB[s * M + m] = sigm(p + cw + br[0]);
    }
    if (s == 0 && l16 < NG) {
      float gv = sm.part2[row][0][1 + l16] + sm.part2[row][1][1 + l16] +
                 sm.part2[row][2][1 + l16] + sm.part2[row][3][1 + l16];
      out[PTS + (long long)m * NG + l16] = gv + bg[l16];
    }
  }
}

// ---------------- k_vocab: 256x128 tiles, BK=64 phases, e=exp(logit) bf16 ----------------
__global__ __launch_bounds__(512) void k_vocab(
    const u16* __restrict__ hAllH, const u16* __restrict__ ebf,
    u16* __restrict__ ebuf)
{
  __shared__ u16 Bs[2][8192];     // [buf][128 rows][64 cols] bf16, row=128B, swz f(r)=r&7
  const int bx = blockIdx.x;
  const int tid = threadIdx.x;
  const int wave = tid >> 6, lane = tid & 63;
  const int bxs = (bx & 7) * (NVB / 8) + (bx >> 3);
  const int nb = bxs / NMP;
  const int mp = bxs % NMP;
  const int n0 = nb * 128;
  const int m0 = mp * 256;
  const int wm = wave >> 1, wn = wave & 1;
  const int lrow = lane & 15;
  const int c16 = lane >> 4;
  const int sr0 = wave * 8 + (lane >> 3);       // issue-0 row; issue-1 = +64
  const int slot = lane & 7;
  f32x4 acc[4][4] = {};

  const u16* aBase = hAllH + (size_t)(m0 + wm * 64 + lrow) * KP + c16 * 8;
  const u16* bS0 = ebf + (size_t)(n0 + sr0) * KP + (size_t)((slot ^ (sr0 & 7)) * 8);
  const u16* bS1 = ebf + (size_t)(n0 + sr0 + 64) * KP + (size_t)((slot ^ ((sr0 + 64) & 7)) * 8);

  gload16(bS0, &Bs[0][wave * 512]);
  gload16(bS1, &Bs[0][4096 + wave * 512]);
  int cur = 0;
#pragma unroll 1
  for (int p = 0; p < 7; ++p) {
    const int kb = p * 64;
    bfrag a[4][2];
#pragma unroll
    for (int r = 0; r < 4; ++r) {
      a[r][0] = *(const bfrag*)(aBase + r * 16 * KP + kb);
      a[r][1] = *(const bfrag*)(aBase + r * 16 * KP + kb + 32);
    }
    if (p < 6) {
      gload16(bS0 + kb + 64, &Bs[cur ^ 1][wave * 512]);
      gload16(bS1 + kb + 64, &Bs[cur ^ 1][4096 + wave * 512]);
      asm volatile("s_waitcnt vmcnt(10)" ::: "memory");   // force stage(p); leave A(8)+stage(p+1)(2)
    } else {
      asm volatile("s_waitcnt vmcnt(8)" ::: "memory");
    }
    __builtin_amdgcn_sched_barrier(0);
    __builtin_amdgcn_s_barrier();
    const u16* Bb = Bs[cur];
#pragma unroll
    for (int ks = 0; ks < 2; ++ks) {
      bfrag bfv[4];
#pragma unroll
      for (int nn = 0; nn < 4; ++nn) {
        const int brr = wn * 64 + nn * 16 + lrow;
        const int g = (ks * 4 + c16) ^ (brr & 7);
        bfv[nn] = *(const bfrag*)&Bb[brr * 64 + g * 8];
      }
#pragma unroll
      for (int nn = 0; nn < 4; ++nn) {
#pragma unroll
        for (int r = 0; r < 4; ++r)
          acc[r][nn] = __builtin_amdgcn_mfma_f32_16x16x32_bf16(a[r][ks], bfv[nn], acc[r][nn], 0, 0, 0);
      }
    }
    __builtin_amdgcn_sched_barrier(0);
    __builtin_amdgcn_s_barrier();
    cur ^= 1;
  }

  // epilogue: e = exp(logit) -> bf16 store (scale applied in k_merge)
  const int orow = (lane >> 4) << 2, ocol = lane & 15;
  const int mbase = (m0 & 511);
#pragma unroll
  for (int af = 0; af < 4; ++af) {
#pragma unroll
    for (int r = 0; r < 4; ++r) {
      const int rl = wm * 64 + af * 16 + orow + r;
      if (mbase + rl >= M && mbase + rl < MP) continue;   // pad row
      const size_t R = (size_t)m0 + rl;
#pragma unroll
      for (int nn = 0; nn < 4; ++nn) {
        const int gn = n0 + wn * 64 + nn * 16 + ocol;
        if (gn < V) ebuf[R * VP + gn] = f2bfn(__expf(acc[af][nn][r]));
      }
    }
  }
}

// ---------------- k_merge: row-sum from ebuf, scale, write, scatter ----------------
__global__ __launch_bounds__(512) void k_merge(
    const u16* __restrict__ ebuf, const float* __restrict__ pgenB,
    const float* __restrict__ attnB, const int* __restrict__ story,
    float* __restrict__ out)
{
  const int bxi = blockIdx.x;
  const int s = bxi / M, m = bxi % M, b = m % B;
  const size_t R = (size_t)s * MP + m;
  const int tid = threadIdx.x;
  const int wave = tid >> 6, lane = tid & 63;
  __shared__ float red8[8];
  const u16* erow = ebuf + R * VP;
  bfrag ch[6];
  float sum = 0.f;
#pragma unroll
  for (int j = 0; j < 6; ++j) {
    const int c = j * 512 + tid;
    if (c < VP / 8) {
      ch[j] = *(const bfrag*)(erow + (size_t)c * 8);
#pragma unroll
      for (int e = 0; e < 8; ++e) sum += bf2f((u16)ch[j][e]);
    }
  }
#pragma unroll
  for (int off = 32; off; off >>= 1) sum += __shfl_xor(sum, off);
  if (lane == 0) red8[wave] = sum;
  __syncthreads();
  float Sv = 0.f;
#pragma unroll
  for (int j = 0; j < 8; ++j) Sv += red8[j];
  const float pg = pgenB[s * M + m];
  const float scale = pg / Sv;
  float* orow = out + ((size_t)m * STEPS + s) * V;
#pragma unroll
  for (int j = 0; j < 6; ++j) {
    const int c = j * 512 + tid;
    if (c < V / 8) {
      f32x4 w0, w1;
#pragma unroll
      for (int e = 0; e < 4; ++e) {
        w0[e] = bf2f((u16)ch[j][e]) * scale;
        w1[e] = bf2f((u16)ch[j][4 + e]) * scale;
      }
      *(f32x4*)(orow + (size_t)c * 8) = w0;
      *(f32x4*)(orow + (size_t)c * 8 + 4) = w1;
    }
  }
  __syncthreads();
  const float om = 1.f - pg;
  for (int t = tid; t < T; t += 512) {
    float a = attnB[((size_t)s * M + m) * T + t];
    if (a != 0.f) atomicAdd(orow + story[b * T + t], om * a);
  }
}

// ---------------- launch ----------------

extern "C" void kernel_launch(void* const* d_in, const int* in_sizes, int n_in,
                              void* d_out, int out_size, void* d_ws, size_t ws_size,
                              hipStream_t stream) {
  (void)in_sizes; (void)n_in; (void)out_size; (void)ws_size;
  const float* emb  = (const float*)d_in[0];
  const float* Wih  = (const float*)d_in[1];
  const float* Whh  = (const float*)d_in[2];
  const float* bih  = (const float*)d_in[3];
  const float* bhh  = (const float*)d_in[4];
  const float* Wr   = (const float*)d_in[5];
  const float* br   = (const float*)d_in[6];
  const float* Wg   = (const float*)d_in[7];
  const float* bg   = (const float*)d_in[8];
  const float* semb = (const float*)d_in[9];
  const float* ehid = (const float*)d_in[10];
  const float* enc  = (const float*)d_in[11];
  const int*   lens = (const int*)d_in[12];
  const int*   story= (const int*)d_in[13];
  const int*   tgt  = (const int*)d_in[14];
  float* out = (float*)d_out;

  char* w = (char*)d_ws;
  size_t off = 0;
  auto alloc = [&](size_t n) -> void* {
    void* p = w + off;
    off = (off + n + 255) & ~(size_t)255;
    return p;
  };
  u16* ebf    = (u16*)alloc((size_t)VP * KP * 2);
  u16* wihH   = (u16*)alloc((size_t)NWP * KP * 2);
  u16* wihL   = (u16*)alloc((size_t)NWP * KP * 2);
  u16* whhH   = (u16*)alloc((size_t)NWP * KP * 2);
  u16* whhL   = (u16*)alloc((size_t)NWP * KP * 2);
  u16* decH   = (u16*)alloc((size_t)STEPS * MP * KP * 2);
  u16* decL   = (u16*)alloc((size_t)STEPS * MP * KP * 2);
  float* dec  = (float*)alloc((size_t)STEPS * M * H * 4);
  float* h0F  = (float*)alloc((size_t)M * H * 4);
  u16* h0H    = (u16*)alloc((size_t)MP * KP * 2);
  u16* h0L    = (u16*)alloc((size_t)MP * KP * 2);
  u16* hAllH  = (u16*)alloc((size_t)MR * KP * 2);
  u16* hAllL  = (u16*)alloc((size_t)MR * KP * 2);
  float* hallF= (float*)alloc((size_t)STEPS * M * H * 4);
  float* gi   = (float*)alloc((size_t)MR * H3 * 4);
  float* attnB= (float*)alloc((size_t)STEPS * M * T * 4);
  float* pgenB= (float*)alloc((size_t)STEPS * M * 4);
  u16* ebuf   = (u16*)alloc((size_t)MR * VP * 2);
  u16* encbK  = (u16*)alloc((size_t)B * 400 * TPAD * 2);
  u16* encT   = (u16*)alloc((size_t)B * 400 * TPAD * 2);

  k_init<<<N_INIT, 256, 0, stream>>>(emb, enc, Wih, Whh, semb, ehid, tgt,
      ebf, encbK, encT, wihH, wihL, whhH, whhL, dec, decH, decL,
      h0F, h0H, h0L, hAllH, hAllL, ebuf);
  // all-steps gi = dec @ Wih^T + bih
  k_gemm64s<<<dim3((H3 + 63) / 64, MR / 64), 256, 0, stream>>>(
      decH, decL, wihH, wihL, bih, gi, MR, H3, H3);

  // serial GRU spine: fused gh-GEMM + cell per step
  for (int s = 0; s < STEPS; ++s) {
    const u16* pH = (s == 0) ? h0H : hAllH + (size_t)(s - 1) * MP * KP;
    const u16* pL = (s == 0) ? h0L : hAllL + (size_t)(s - 1) * MP * KP;
    const float* pF = (s == 0) ? h0F : hallF + (size_t)(s - 1) * M * H;
    k_grustep<<<dim3((H + 63) / 64, (M + 63) / 64), 256, 0, stream>>>(
        pH, pL, pF, whhH, whhL, bhh, gi + (size_t)s * MP * H3,
        hallF + (size_t)s * M * H,
        hAllH + (size_t)s * MP * KP, hAllL + (size_t)s * MP * KP);
  }

  // batched parallel phase
  k_vocab<<<NVB, 512, 0, stream>>>(hAllH, ebf, ebuf);
  k_attn<<<STEPS * B, 512, 0, stream>>>(hAllH, hAllL, hallF, encbK, encT, lens,
                                        dec, Wr, br, Wg, bg, attnB, pgenB, out);
  k_merge<<<STEPS * M, 512, 0, stream>>>(ebuf, pgenB, attnB, story, out);
}

// Round 10
// 606.081 us; speedup vs baseline: 1.2036x; 1.2036x over previous
//
#include <hip/hip_runtime.h>
#include <hip/hip_bf16.h>

#define DEV __device__ __forceinline__

constexpr int B = 16, T = 400, H = 400, V = 22000, S = 30, STEPS = 8, NG = 3;
constexpr int M  = S * B;      // 480
constexpr int H3 = 3 * H;      // 1200
constexpr int KP = 416;        // K padded to 13*32
constexpr int VP = 22016;      // V padded to 172*128
constexpr int MP = 512;        // M padded (per step slot)
constexpr int MR = STEPS * MP; // 4096
constexpr int NWP = 1280;
constexpr int NBLK = VP / 128; // 172
constexpr int NMP = MR / 256;  // 16
constexpr int NVB = NBLK * NMP;// 2752 (8 | NVB)
constexpr int TPAD = 416;
constexpr int PLD = 424;
constexpr long long PTS = (long long)S * B * STEPS * V;

typedef __attribute__((ext_vector_type(8))) short bfrag;
typedef __attribute__((ext_vector_type(4))) float f32x4;
typedef unsigned short u16;

DEV u16 f2bf(float x) {                 // manual RNE (init/split paths)
  unsigned u = __float_as_uint(x);
  u += 0x7FFFu + ((u >> 16) & 1u);
  return (u16)(u >> 16);
}
DEV u16 f2bfn(float x) {                // native cvt (hot paths)
  __hip_bfloat16 h = __float2bfloat16(x);
  union { __hip_bfloat16 b; u16 u; } cv; cv.b = h; return cv.u;
}
DEV float bf2f(u16 h) { return __uint_as_float(((unsigned)h) << 16); }
DEV float sigm(float x) { return 1.0f / (1.0f + __expf(-x)); }

DEV void gload16(const u16* g, u16* l) {
  __builtin_amdgcn_global_load_lds(
      (const __attribute__((address_space(1))) void*)g,
      (__attribute__((address_space(3))) void*)l, 16, 0, 0);
}

// ---------------- merged init (KP=416) ----------------
constexpr int N_EMB = VP * KP / 256;               // 35776
constexpr int N_ENC = B * 400 * TPAD / 256;        // 10400
constexpr int N_W   = NWP * KP / 256;              // 2080
constexpr int N_DEC = STEPS * MP * KP / 256;       // 6656
constexpr int N_H0  = MP * KP / 256;               // 832
constexpr int N_ZP  = STEPS * (MP - M) * KP / 256; // 416
constexpr int N_ZE  = MR * 16 / 256;               // 256
constexpr int N_INIT = N_EMB + N_ENC + N_W + N_DEC + N_H0 + N_ZP + N_ZE;

__global__ __launch_bounds__(256) void k_init(
    const float* __restrict__ emb, const float* __restrict__ enc,
    const float* __restrict__ Wih, const float* __restrict__ Whh,
    const float* __restrict__ semb, const float* __restrict__ ehid,
    const int* __restrict__ tgt,
    u16* __restrict__ ebf, u16* __restrict__ encbK, u16* __restrict__ encT,
    u16* __restrict__ wihH, u16* __restrict__ wihL,
    u16* __restrict__ whhH, u16* __restrict__ whhL,
    float* __restrict__ dec, u16* __restrict__ decH, u16* __restrict__ decL,
    float* __restrict__ h0F, u16* __restrict__ h0H, u16* __restrict__ h0L,
    u16* __restrict__ hAllH, u16* __restrict__ hAllL, u16* __restrict__ ebuf)
{
  int bx = blockIdx.x;
  const int tid = threadIdx.x;
  if (bx < N_EMB) {
    int i = bx * 256 + tid;
    int v = i / KP, k = i % KP;
    ebf[i] = f2bf((v < V && k < H) ? emb[(long long)v * H + k] : 0.f);
    return;
  }
  bx -= N_EMB;
  if (bx < N_ENC) {
    int i = bx * 256 + tid;
    int c = i % TPAD, r = (i / TPAD) % 400, b = i / (TPAD * 400);
    encbK[i] = f2bf((c < H) ? enc[((size_t)b * T + r) * H + c] : 0.f);
    encT[i]  = f2bf((c < T) ? enc[((size_t)b * T + c) * H + r] : 0.f);
    return;
  }
  bx -= N_ENC;
  if (bx < N_W) {
    int i = bx * 256 + tid;
    int n = i / KP, k = i % KP;
    float v1 = (n < H3 && k < H) ? Wih[n * H + k] : 0.f;
    u16 h1 = f2bf(v1);
    wihH[i] = h1; wihL[i] = f2bf(v1 - bf2f(h1));
    float v2 = (n < H3 && k < H) ? Whh[n * H + k] : 0.f;
    u16 h2 = f2bf(v2);
    whhH[i] = h2; whhL[i] = f2bf(v2 - bf2f(h2));
    return;
  }
  bx -= N_W;
  if (bx < N_DEC) {
    int i = bx * 256 + tid;
    int k = i % KP, m = (i / KP) % MP, s = i / (KP * MP);
    float val = 0.f;
    if (m < M && k < H) {
      int slot = m / B, b = m % B;
      if (s == 0) val = semb[slot * H + k];
      else        val = emb[(long long)tgt[(b * S + slot) * STEPS + (s - 1)] * H + k];
      dec[((long long)s * M + m) * H + k] = val;
    }
    u16 hi = f2bf(val);
    decH[i] = hi; decL[i] = f2bf(val - bf2f(hi));
    return;
  }
  bx -= N_DEC;
  if (bx < N_H0) {
    int i = bx * 256 + tid;
    int k = i % KP, m = i / KP;
    float val = (m < M && k < H) ? ehid[(m % B) * H + k] : 0.f;
    if (m < M && k < H) h0F[m * H + k] = val;
    u16 hi = f2bf(val);
    h0H[i] = hi; h0L[i] = f2bf(val - bf2f(hi));
    return;
  }
  bx -= N_H0;
  if (bx < N_ZP) {
    int i = bx * 256 + tid;
    int k = i % KP;
    int row = M + (i / KP) % (MP - M);
    int s = i / (KP * (MP - M));
    size_t idx = ((size_t)s * MP + row) * KP + k;
    hAllH[idx] = 0; hAllL[idx] = 0;
    return;
  }
  bx -= N_ZP;
  {
    int i = bx * 256 + tid;           // MR*16: zero ebuf cols [V,VP)
    int row = i / 16, col = V + (i % 16);
    ebuf[(size_t)row * VP + col] = 0;
  }
}

// ---------------- 64x64-tile SPLIT GEMM (gi batched, gh per step) ----------------
__global__ __launch_bounds__(256) void k_gemm64s(
    const u16* __restrict__ Ahi, const u16* __restrict__ Alo,
    const u16* __restrict__ Bmh, const u16* __restrict__ Bml,
    const float* __restrict__ bias, float* __restrict__ C,
    int Mvalid, int Nvalid, int Cstride)
{
  __shared__ u16 BsH[64 * 32], BsL[64 * 32];
  const int tid = threadIdx.x;
  const int wave = tid >> 6, lane = tid & 63;
  const int wm = wave >> 1, wn = wave & 1;
  const int n0 = blockIdx.x * 64;
  const int m0 = blockIdx.y * 64;
  const int lrow = lane & 15;
  const int c16 = lane >> 4;
  const int srow = tid >> 2;
  const int sg = (tid & 3) ^ (srow & 3);
  f32x4 acc[2][2] = {};

  const u16* aH = Ahi + (size_t)(m0 + wm * 32 + lrow) * KP + c16 * 8;
  const u16* aL = Alo + (size_t)(m0 + wm * 32 + lrow) * KP + c16 * 8;
  const u16* bHs = Bmh + (size_t)(n0 + srow) * KP + sg * 8;
  const u16* bLs = Bml + (size_t)(n0 + srow) * KP + sg * 8;
  u16* lBH = BsH + wave * 512;
  u16* lBL = BsL + wave * 512;

  for (int kk = 0; kk < KP / 32; ++kk) {
    const int kb = kk * 32;
    gload16(bHs + kb, lBH);
    gload16(bLs + kb, lBL);
    __syncthreads();
    bfrag a0h = *(const bfrag*)(aH + kb);
    bfrag a1h = *(const bfrag*)(aH + 16 * KP + kb);
    bfrag a0l = *(const bfrag*)(aL + kb);
    bfrag a1l = *(const bfrag*)(aL + 16 * KP + kb);
#pragma unroll
    for (int nn = 0; nn < 2; ++nn) {
      const int br = wn * 32 + nn * 16 + lrow;
      const int goff = br * 32 + ((c16 ^ (br & 3)) << 3);
      bfrag bh = *(const bfrag*)&BsH[goff];
      bfrag bl = *(const bfrag*)&BsL[goff];
      acc[0][nn] = __builtin_amdgcn_mfma_f32_16x16x32_bf16(a0h, bh, acc[0][nn], 0, 0, 0);
      acc[1][nn] = __builtin_amdgcn_mfma_f32_16x16x32_bf16(a1h, bh, acc[1][nn], 0, 0, 0);
      acc[0][nn] = __builtin_amdgcn_mfma_f32_16x16x32_bf16(a0h, bl, acc[0][nn], 0, 0, 0);
      acc[1][nn] = __builtin_amdgcn_mfma_f32_16x16x32_bf16(a1h, bl, acc[1][nn], 0, 0, 0);
      acc[0][nn] = __builtin_amdgcn_mfma_f32_16x16x32_bf16(a0l, bh, acc[0][nn], 0, 0, 0);
      acc[1][nn] = __builtin_amdgcn_mfma_f32_16x16x32_bf16(a1l, bh, acc[1][nn], 0, 0, 0);
    }
    __syncthreads();
  }
  const int orow = (lane >> 4) << 2, ocol = lane & 15;
#pragma unroll
  for (int am = 0; am < 2; ++am) {
#pragma unroll
    for (int nn = 0; nn < 2; ++nn) {
      const int gn = n0 + wn * 32 + nn * 16 + ocol;
      if (gn >= Nvalid) continue;
      const float badd = bias[gn];
#pragma unroll
      for (int r = 0; r < 4; ++r) {
        const int gm = m0 + wm * 32 + am * 16 + orow + r;
        if (gm < Mvalid) C[(long long)gm * Cstride + gn] = acc[am][nn][r] + badd;
      }
    }
  }
}

// ---------------- GRU cell ----------------
__global__ __launch_bounds__(512) void k_cell(const float* __restrict__ gi_s,
                                              const float* __restrict__ gh,
                                              const float* __restrict__ hprevF,
                                              float* __restrict__ hcurF,
                                              u16* __restrict__ hHc, u16* __restrict__ hLc) {
  int i = blockIdx.x * 512 + threadIdx.x;
  if (i >= M * H) return;
  int k = i % H, m = i / H;
  float ir = gi_s[m * H3 + k],         hr = gh[m * H3 + k];
  float iz = gi_s[m * H3 + H + k],     hz = gh[m * H3 + H + k];
  float in_ = gi_s[m * H3 + 2*H + k],  hn = gh[m * H3 + 2*H + k];
  float rr = sigm(ir + hr);
  float z = sigm(iz + hz);
  float n = tanhf(in_ + rr * hn);
  float hv = (1.f - z) * n + z * hprevF[i];
  hcurF[i] = hv;
  u16 hb = f2bf(hv);
  hHc[m * KP + k] = hb;
  hLc[m * KP + k] = f2bf(hv - bf2f(hb));
}

// ---------------- k_attn: MFMA attention, one block per (s,b) ----------------
struct SMatt {
  u16 P[32 * PLD];
  float partm[32][4];
  float parts[32][4];
  float rowred[32];
  float part2[32][4][4];
};

__global__ __launch_bounds__(512) void k_attn(
    const u16* __restrict__ hAllH, const u16* __restrict__ hAllL,
    const float* __restrict__ hallF,
    const u16* __restrict__ encbK, const u16* __restrict__ encT,
    const int* __restrict__ lens, const float* __restrict__ dec,
    const float* __restrict__ Wr, const float* __restrict__ br,
    const float* __restrict__ Wg, const float* __restrict__ bg,
    float* __restrict__ attnB, float* __restrict__ pgenB, float* __restrict__ out)
{
  __shared__ SMatt sm;
  const int s = blockIdx.x >> 4;
  const int b = blockIdx.x & 15;
  const int tid = threadIdx.x;
  const int wave = tid >> 6, lane = tid & 63;
  const int mt = wave & 1;
  const int wg = wave >> 1;
  const int lrow = lane & 15;
  const int c16 = lane >> 4;
  const int len = lens[b];
  const int rbase = mt * 16 + c16 * 4;

  for (int idx = tid; idx < 32 * 24; idx += 512)
    sm.P[(idx / 24) * PLD + 400 + (idx % 24)] = 0;

  f32x4 acc[7] = {};
  {
    const size_t arow = (size_t)s * MP + (size_t)(mt * 16 + lrow) * B + b;
    const u16* aHp = hAllH + arow * KP + c16 * 8;
    const u16* aLp = hAllL + arow * KP + c16 * 8;
    const u16* bBase = encbK + (size_t)b * 400 * TPAD + c16 * 8;
    for (int kk = 0; kk < 13; ++kk) {
      bfrag ah = *(const bfrag*)(aHp + kk * 32);
      bfrag al = *(const bfrag*)(aLp + kk * 32);
#pragma unroll
      for (int i = 0; i < 7; ++i) {
        const int jt = wg + 4 * i;
        if (jt < 25) {
          bfrag bv = *(const bfrag*)(bBase + (size_t)(jt * 16 + lrow) * TPAD + kk * 32);
          acc[i] = __builtin_amdgcn_mfma_f32_16x16x32_bf16(ah, bv, acc[i], 0, 0, 0);
          acc[i] = __builtin_amdgcn_mfma_f32_16x16x32_bf16(al, bv, acc[i], 0, 0, 0);
        }
      }
    }
  }

  {
    float pm[4] = {-1e30f, -1e30f, -1e30f, -1e30f};
#pragma unroll
    for (int i = 0; i < 7; ++i) {
      const int jt = wg + 4 * i;
      if (jt >= 25) continue;
      const int t = jt * 16 + lrow;
      const bool ok = t < len;
#pragma unroll
      for (int rr = 0; rr < 4; ++rr) pm[rr] = fmaxf(pm[rr], ok ? acc[i][rr] : -1e30f);
    }
#pragma unroll
    for (int d = 1; d < 16; d <<= 1) {
#pragma unroll
      for (int rr = 0; rr < 4; ++rr) pm[rr] = fmaxf(pm[rr], __shfl_xor(pm[rr], d));
    }
    if (lrow == 0) {
#pragma unroll
      for (int rr = 0; rr < 4; ++rr) sm.partm[rbase + rr][wg] = pm[rr];
    }
  }
  __syncthreads();
  if (tid < 32)
    sm.rowred[tid] = fmaxf(fmaxf(sm.partm[tid][0], sm.partm[tid][1]),
                           fmaxf(sm.partm[tid][2], sm.partm[tid][3]));
  __syncthreads();
  float Mx[4];
#pragma unroll
  for (int rr = 0; rr < 4; ++rr) Mx[rr] = sm.rowred[rbase + rr];
  {
    float ps[4] = {0.f, 0.f, 0.f, 0.f};
#pragma unroll
    for (int i = 0; i < 7; ++i) {
      const int jt = wg + 4 * i;
      if (jt >= 25) continue;
      const int t = jt * 16 + lrow;
      const bool ok = t < len;
#pragma unroll
      for (int rr = 0; rr < 4; ++rr) {
        float e = ok ? __expf(acc[i][rr] - Mx[rr]) : 0.f;
        acc[i][rr] = e;
        ps[rr] += e;
      }
    }
#pragma unroll
    for (int d = 1; d < 16; d <<= 1) {
#pragma unroll
      for (int rr = 0; rr < 4; ++rr) ps[rr] += __shfl_xor(ps[rr], d);
    }
    if (lrow == 0) {
#pragma unroll
      for (int rr = 0; rr < 4; ++rr) sm.parts[rbase + rr][wg] = ps[rr];
    }
  }
  __syncthreads();
  if (tid < 32)
    sm.rowred[tid] = sm.parts[tid][0] + sm.parts[tid][1] + sm.parts[tid][2] + sm.parts[tid][3];
  __syncthreads();
  {
    float inv[4];
#pragma unroll
    for (int rr = 0; rr < 4; ++rr) inv[rr] = 1.f / sm.rowred[rbase + rr];
#pragma unroll
    for (int i = 0; i < 7; ++i) {
      const int jt = wg + 4 * i;
      if (jt >= 25) continue;
      const int t = jt * 16 + lrow;
#pragma unroll
      for (int rr = 0; rr < 4; ++rr) {
        const int row = rbase + rr;
        const float p = acc[i][rr] * inv[rr];
        sm.P[row * PLD + t] = f2bfn(p);
        if (row < 30) attnB[((size_t)s * M + row * B + b) * T + t] = p;
      }
    }
  }
  __syncthreads();

  f32x4 acc2[7] = {};
  {
    const u16* bBase = encT + (size_t)b * 400 * TPAD + c16 * 8;
    const u16* aP = sm.P + (mt * 16 + lrow) * PLD + c16 * 8;
    for (int kk = 0; kk < 13; ++kk) {
      bfrag ap = *(const bfrag*)(aP + kk * 32);
#pragma unroll
      for (int i = 0; i < 7; ++i) {
        const int jk = wg + 4 * i;
        if (jk < 25) {
          bfrag bv = *(const bfrag*)(bBase + (size_t)(jk * 16 + lrow) * TPAD + kk * 32);
          acc2[i] = __builtin_amdgcn_mfma_f32_16x16x32_bf16(ap, bv, acc2[i], 0, 0, 0);
        }
      }
    }
  }
  {
    float pw[4] = {0.f, 0.f, 0.f, 0.f};
    float pg0[4] = {0.f, 0.f, 0.f, 0.f};
    float pg1[4] = {0.f, 0.f, 0.f, 0.f};
    float pg2[4] = {0.f, 0.f, 0.f, 0.f};
    const bool do_g = (s == 0);
#pragma unroll
    for (int i = 0; i < 7; ++i) {
      const int jk = wg + 4 * i;
      if (jk >= 25) continue;
      const int k = jk * 16 + lrow;
      const float wr = Wr[H + k];
      float w0 = 0.f, w1 = 0.f, w2 = 0.f;
      if (do_g) { w0 = Wg[k]; w1 = Wg[H + k]; w2 = Wg[2 * H + k]; }
#pragma unroll
      for (int rr = 0; rr < 4; ++rr) {
        const float v = acc2[i][rr];
        pw[rr] = fmaf(v, wr, pw[rr]);
        if (do_g) {
          pg0[rr] = fmaf(v, w0, pg0[rr]);
          pg1[rr] = fmaf(v, w1, pg1[rr]);
          pg2[rr] = fmaf(v, w2, pg2[rr]);
        }
      }
    }
#pragma unroll
    for (int d = 1; d < 16; d <<= 1) {
#pragma unroll
      for (int rr = 0; rr < 4; ++rr) {
        pw[rr] += __shfl_xor(pw[rr], d);
        pg0[rr] += __shfl_xor(pg0[rr], d);
        pg1[rr] += __shfl_xor(pg1[rr], d);
        pg2[rr] += __shfl_xor(pg2[rr], d);
      }
    }
    if (lrow == 0) {
#pragma unroll
      for (int rr = 0; rr < 4; ++rr) {
        sm.part2[rbase + rr][wg][0] = pw[rr];
        sm.part2[rbase + rr][wg][1] = pg0[rr];
        sm.part2[rbase + rr][wg][2] = pg1[rr];
        sm.part2[rbase + rr][wg][3] = pg2[rr];
      }
    }
  }
  __syncthreads();

  if (tid < 480) {
    const int row = tid >> 4;
    const int l16 = tid & 15;
    const int m = row * B + b;
    const float* hF = hallF + ((size_t)s * M + m) * H;
    const float* dF = dec + ((size_t)s * M + m) * H;
    float p = 0.f;
    for (int j = 0; j < 25; ++j) {
      const int k = l16 + 16 * j;
      p += hF[k] * Wr[k] + dF[k] * Wr[2 * H + k];
    }
#pragma unroll
    for (int d = 1; d < 16; d <<= 1) p += __shfl_xor(p, d);
    if (l16 == 0) {
      float cw = sm.part2[row][0][0] + sm.part2[row][1][0] +
                 sm.part2[row][2][0] + sm.part2[row][3][0];
      pgenB[s * M + m] = sigm(p + cw + br[0]);
    }
    if (s == 0 && l16 < NG) {
      float gv = sm.part2[row][0][1 + l16] + sm.part2[row][1][1 + l16] +
                 sm.part2[row][2][1 + l16] + sm.part2[row][3][1 + l16];
      out[PTS + (long long)m * NG + l16] = gv + bg[l16];
    }
  }
}

// ---------------- k_vocab: R8 pipeline (256x128, BK=32, dbuf vmcnt(5)), exp-direct epilogue ----------------
__global__ __launch_bounds__(512) void k_vocab(
    const u16* __restrict__ hAllH, const u16* __restrict__ ebf,
    u16* __restrict__ ebuf)
{
  __shared__ u16 Bs[2 * 4096];
  const int bx = blockIdx.x;
  const int tid = threadIdx.x;
  const int wave = tid >> 6, lane = tid & 63;
  const int bxs = (bx & 7) * (NVB / 8) + (bx >> 3);   // bijective XCD swizzle
  const int nb = bxs / NMP;
  const int mp = bxs % NMP;
  const int n0 = nb * 128;
  const int m0 = mp * 256;
  const int wm = wave >> 1, wn = wave & 1;
  const int lrow = lane & 15;
  const int c16 = lane >> 4;
  const int srow = tid >> 2;
  const int sg = (tid & 3) ^ (srow & 3);
  f32x4 acc[4][4] = {};

  const u16* aBase = hAllH + (size_t)(m0 + wm * 64 + lrow) * KP + c16 * 8;
  const u16* bS = ebf + (size_t)(n0 + srow) * KP + sg * 8;
  u16* lB0 = Bs + wave * 512;
  u16* lB1 = Bs + 4096 + wave * 512;

  gload16(bS, lB0);
  int cur = 0;
#pragma unroll 1
  for (int kk = 0; kk < 13; ++kk) {
    bfrag af0 = *(const bfrag*)(aBase + 0 * 16 * KP + kk * 32);
    bfrag af1 = *(const bfrag*)(aBase + 1 * 16 * KP + kk * 32);
    bfrag af2 = *(const bfrag*)(aBase + 2 * 16 * KP + kk * 32);
    bfrag af3 = *(const bfrag*)(aBase + 3 * 16 * KP + kk * 32);
    if (kk < 12) {
      gload16(bS + (kk + 1) * 32, cur ? lB0 : lB1);
      asm volatile("s_waitcnt vmcnt(5)" ::: "memory");
    } else {
      asm volatile("s_waitcnt vmcnt(4)" ::: "memory");
    }
    __builtin_amdgcn_sched_barrier(0);
    __builtin_amdgcn_s_barrier();
    const u16* Bb = Bs + (cur ? 4096 : 0);
    bfrag bfv[4];
#pragma unroll
    for (int nn = 0; nn < 4; ++nn) {
      const int brr = wn * 64 + nn * 16 + lrow;
      bfv[nn] = *(const bfrag*)&Bb[brr * 32 + ((c16 ^ (brr & 3)) << 3)];
    }
#pragma unroll
    for (int nn = 0; nn < 4; ++nn) {
      acc[0][nn] = __builtin_amdgcn_mfma_f32_16x16x32_bf16(af0, bfv[nn], acc[0][nn], 0, 0, 0);
      acc[1][nn] = __builtin_amdgcn_mfma_f32_16x16x32_bf16(af1, bfv[nn], acc[1][nn], 0, 0, 0);
      acc[2][nn] = __builtin_amdgcn_mfma_f32_16x16x32_bf16(af2, bfv[nn], acc[2][nn], 0, 0, 0);
      acc[3][nn] = __builtin_amdgcn_mfma_f32_16x16x32_bf16(af3, bfv[nn], acc[3][nn], 0, 0, 0);
    }
    __builtin_amdgcn_sched_barrier(0);
    __builtin_amdgcn_s_barrier();
    cur ^= 1;
  }

  // epilogue: e = exp(logit) -> bf16 (scale/normalize applied in k_merge)
  const int orow = (lane >> 4) << 2, ocol = lane & 15;
#pragma unroll
  for (int af = 0; af < 4; ++af) {
#pragma unroll
    for (int r = 0; r < 4; ++r) {
      const int rl = wm * 64 + af * 16 + orow + r;
      const size_t R = (size_t)m0 + rl;
      if ((R % MP) >= M) continue;                 // pad row
#pragma unroll
      for (int nn = 0; nn < 4; ++nn) {
        const int gn = n0 + wn * 64 + nn * 16 + ocol;
        if (gn < V) ebuf[R * VP + gn] = f2bfn(__expf(acc[af][nn][r]));
      }
    }
  }
}

// ---------------- k_merge: row-sum from ebuf, scale, write, scatter ----------------
__global__ __launch_bounds__(512) void k_merge(
    const u16* __restrict__ ebuf, const float* __restrict__ pgenB,
    const float* __restrict__ attnB, const int* __restrict__ story,
    float* __restrict__ out)
{
  const int bxi = blockIdx.x;
  const int s = bxi / M, m = bxi % M, b = m % B;
  const size_t R = (size_t)s * MP + m;
  const int tid = threadIdx.x;
  const int wave = tid >> 6, lane = tid & 63;
  __shared__ float red8[8];
  const u16* erow = ebuf + R * VP;
  bfrag ch[6];
  float sum = 0.f;
#pragma unroll
  for (int j = 0; j < 6; ++j) {
    const int c = j * 512 + tid;
    if (c < VP / 8) {
      ch[j] = *(const bfrag*)(erow + (size_t)c * 8);
#pragma unroll
      for (int e = 0; e < 8; ++e) sum += bf2f((u16)ch[j][e]);
    }
  }
#pragma unroll
  for (int off = 32; off; off >>= 1) sum += __shfl_xor(sum, off);
  if (lane == 0) red8[wave] = sum;
  __syncthreads();
  float Sv = 0.f;
#pragma unroll
  for (int j = 0; j < 8; ++j) Sv += red8[j];
  const float pg = pgenB[s * M + m];
  const float scale = pg / Sv;
  float* orow = out + ((size_t)m * STEPS + s) * V;
#pragma unroll
  for (int j = 0; j < 6; ++j) {
    const int c = j * 512 + tid;
    if (c < V / 8) {
      f32x4 w0, w1;
#pragma unroll
      for (int e = 0; e < 4; ++e) {
        w0[e] = bf2f((u16)ch[j][e]) * scale;
        w1[e] = bf2f((u16)ch[j][4 + e]) * scale;
      }
      *(f32x4*)(orow + (size_t)c * 8) = w0;
      *(f32x4*)(orow + (size_t)c * 8 + 4) = w1;
    }
  }
  __syncthreads();
  const float om = 1.f - pg;
  for (int t = tid; t < T; t += 512) {
    float a = attnB[((size_t)s * M + m) * T + t];
    if (a != 0.f) atomicAdd(orow + story[b * T + t], om * a);
  }
}

// ---------------- launch ----------------

extern "C" void kernel_launch(void* const* d_in, const int* in_sizes, int n_in,
                              void* d_out, int out_size, void* d_ws, size_t ws_size,
                              hipStream_t stream) {
  (void)in_sizes; (void)n_in; (void)out_size; (void)ws_size;
  const float* emb  = (const float*)d_in[0];
  const float* Wih  = (const float*)d_in[1];
  const float* Whh  = (const float*)d_in[2];
  const float* bih  = (const float*)d_in[3];
  const float* bhh  = (const float*)d_in[4];
  const float* Wr   = (const float*)d_in[5];
  const float* br   = (const float*)d_in[6];
  const float* Wg   = (const float*)d_in[7];
  const float* bg   = (const float*)d_in[8];
  const float* semb = (const float*)d_in[9];
  const float* ehid = (const float*)d_in[10];
  const float* enc  = (const float*)d_in[11];
  const int*   lens = (const int*)d_in[12];
  const int*   story= (const int*)d_in[13];
  const int*   tgt  = (const int*)d_in[14];
  float* out = (float*)d_out;

  char* w = (char*)d_ws;
  size_t off = 0;
  auto alloc = [&](size_t n) -> void* {
    void* p = w + off;
    off = (off + n + 255) & ~(size_t)255;
    return p;
  };
  u16* ebf    = (u16*)alloc((size_t)VP * KP * 2);
  u16* wihH   = (u16*)alloc((size_t)NWP * KP * 2);
  u16* wihL   = (u16*)alloc((size_t)NWP * KP * 2);
  u16* whhH   = (u16*)alloc((size_t)NWP * KP * 2);
  u16* whhL   = (u16*)alloc((size_t)NWP * KP * 2);
  u16* decH   = (u16*)alloc((size_t)STEPS * MP * KP * 2);
  u16* decL   = (u16*)alloc((size_t)STEPS * MP * KP * 2);
  float* dec  = (float*)alloc((size_t)STEPS * M * H * 4);
  float* h0F  = (float*)alloc((size_t)M * H * 4);
  u16* h0H    = (u16*)alloc((size_t)MP * KP * 2);
  u16* h0L    = (u16*)alloc((size_t)MP * KP * 2);
  u16* hAllH  = (u16*)alloc((size_t)MR * KP * 2);
  u16* hAllL  = (u16*)alloc((size_t)MR * KP * 2);
  float* hallF= (float*)alloc((size_t)STEPS * M * H * 4);
  float* gi   = (float*)alloc((size_t)MR * H3 * 4);
  float* gh   = (float*)alloc((size_t)M * H3 * 4);
  float* attnB= (float*)alloc((size_t)STEPS * M * T * 4);
  float* pgenB= (float*)alloc((size_t)STEPS * M * 4);
  u16* ebuf   = (u16*)alloc((size_t)MR * VP * 2);
  u16* encbK  = (u16*)alloc((size_t)B * 400 * TPAD * 2);
  u16* encT   = (u16*)alloc((size_t)B * 400 * TPAD * 2);

  k_init<<<N_INIT, 256, 0, stream>>>(emb, enc, Wih, Whh, semb, ehid, tgt,
      ebf, encbK, encT, wihH, wihL, whhH, whhL, dec, decH, decL,
      h0F, h0H, h0L, hAllH, hAllL, ebuf);
  // all-steps gi = dec @ Wih^T + bih
  k_gemm64s<<<dim3((H3 + 63) / 64, MR / 64), 256, 0, stream>>>(
      decH, decL, wihH, wihL, bih, gi, MR, H3, H3);

  // serial GRU spine: gh GEMM + cell per step (R8-proven)
  for (int s = 0; s < STEPS; ++s) {
    const u16* pH = (s == 0) ? h0H : hAllH + (size_t)(s - 1) * MP * KP;
    const u16* pL = (s == 0) ? h0L : hAllL + (size_t)(s - 1) * MP * KP;
    const float* pF = (s == 0) ? h0F : hallF + (size_t)(s - 1) * M * H;
    k_gemm64s<<<dim3((H3 + 63) / 64, (M + 63) / 64), 256, 0, stream>>>(
        pH, pL, whhH, whhL, bhh, gh, M, H3, H3);
    k_cell<<<(M * H + 511) / 512, 512, 0, stream>>>(
        gi + (size_t)s * MP * H3, gh, pF,
        hallF + (size_t)s * M * H,
        hAllH + (size_t)s * MP * KP, hAllL + (size_t)s * MP * KP);
  }

  // batched parallel phase
  k_vocab<<<NVB, 512, 0, stream>>>(hAllH, ebf, ebuf);
  k_attn<<<STEPS * B, 512, 0, stream>>>(hAllH, hAllL, hallF, encbK, encT, lens,
                                        dec, Wr, br, Wg, bg, attnB, pgenB, out);
  k_merge<<<STEPS * M, 512, 0, stream>>>(ebuf, pgenB, attnB, story, out);
}

// Round 11
// 605.096 us; speedup vs baseline: 1.2056x; 1.0016x over previous
//
#include <hip/hip_runtime.h>
#include <hip/hip_bf16.h>

#define DEV __device__ __forceinline__

constexpr int B = 16, T = 400, H = 400, V = 22000, S = 30, STEPS = 8, NG = 3;
constexpr int M  = S * B;      // 480
constexpr int H3 = 3 * H;      // 1200
constexpr int KP = 416;        // K padded to 13*32
constexpr int VP = 22016;      // V padded to 172*128
constexpr int MP = 512;        // M padded (per step slot)
constexpr int MR = STEPS * MP; // 4096
constexpr int NWP = 1280;
constexpr int NBLK = VP / 128; // 172
constexpr int NMP = MR / 256;  // 16
constexpr int NVB = NBLK * NMP;// 2752 (8 | NVB)
constexpr int TPAD = 416;
constexpr int PLD = 424;
constexpr long long PTS = (long long)S * B * STEPS * V;

typedef __attribute__((ext_vector_type(8))) short bfrag;
typedef __attribute__((ext_vector_type(4))) float f32x4;
typedef unsigned short u16;

DEV u16 f2bf(float x) {                 // manual RNE (init/split paths)
  unsigned u = __float_as_uint(x);
  u += 0x7FFFu + ((u >> 16) & 1u);
  return (u16)(u >> 16);
}
DEV u16 f2bfn(float x) {                // native cvt (hot paths)
  __hip_bfloat16 h = __float2bfloat16(x);
  union { __hip_bfloat16 b; u16 u; } cv; cv.b = h; return cv.u;
}
DEV float bf2f(u16 h) { return __uint_as_float(((unsigned)h) << 16); }
DEV float sigm(float x) { return 1.0f / (1.0f + __expf(-x)); }

DEV void gload16(const u16* g, u16* l) {
  __builtin_amdgcn_global_load_lds(
      (const __attribute__((address_space(1))) void*)g,
      (__attribute__((address_space(3))) void*)l, 16, 0, 0);
}

// ---------------- merged init (KP=416) ----------------
constexpr int N_EMB = VP * KP / 256;               // 35776
constexpr int N_ENC = B * 400 * TPAD / 256;        // 10400
constexpr int N_W   = NWP * KP / 256;              // 2080
constexpr int N_DEC = STEPS * MP * KP / 256;       // 6656
constexpr int N_H0  = MP * KP / 256;               // 832
constexpr int N_ZP  = STEPS * (MP - M) * KP / 256; // 416
constexpr int N_ZE  = MR * 16 / 256;               // 256
constexpr int N_INIT = N_EMB + N_ENC + N_W + N_DEC + N_H0 + N_ZP + N_ZE;

__global__ __launch_bounds__(256) void k_init(
    const float* __restrict__ emb, const float* __restrict__ enc,
    const float* __restrict__ Wih, const float* __restrict__ Whh,
    const float* __restrict__ semb, const float* __restrict__ ehid,
    const int* __restrict__ tgt,
    u16* __restrict__ ebf, u16* __restrict__ encbK, u16* __restrict__ encT,
    u16* __restrict__ wihH, u16* __restrict__ wihL,
    u16* __restrict__ whhH, u16* __restrict__ whhL,
    float* __restrict__ dec, u16* __restrict__ decH, u16* __restrict__ decL,
    float* __restrict__ h0F, u16* __restrict__ h0H, u16* __restrict__ h0L,
    u16* __restrict__ hAllH, u16* __restrict__ hAllL, u16* __restrict__ ebuf)
{
  int bx = blockIdx.x;
  const int tid = threadIdx.x;
  if (bx < N_EMB) {
    int i = bx * 256 + tid;
    int v = i / KP, k = i % KP;
    ebf[i] = f2bf((v < V && k < H) ? emb[(long long)v * H + k] : 0.f);
    return;
  }
  bx -= N_EMB;
  if (bx < N_ENC) {
    int i = bx * 256 + tid;
    int c = i % TPAD, r = (i / TPAD) % 400, b = i / (TPAD * 400);
    encbK[i] = f2bf((c < H) ? enc[((size_t)b * T + r) * H + c] : 0.f);
    encT[i]  = f2bf((c < T) ? enc[((size_t)b * T + c) * H + r] : 0.f);
    return;
  }
  bx -= N_ENC;
  if (bx < N_W) {
    int i = bx * 256 + tid;
    int n = i / KP, k = i % KP;
    float v1 = (n < H3 && k < H) ? Wih[n * H + k] : 0.f;
    u16 h1 = f2bf(v1);
    wihH[i] = h1; wihL[i] = f2bf(v1 - bf2f(h1));
    float v2 = (n < H3 && k < H) ? Whh[n * H + k] : 0.f;
    u16 h2 = f2bf(v2);
    whhH[i] = h2; whhL[i] = f2bf(v2 - bf2f(h2));
    return;
  }
  bx -= N_W;
  if (bx < N_DEC) {
    int i = bx * 256 + tid;
    int k = i % KP, m = (i / KP) % MP, s = i / (KP * MP);
    float val = 0.f;
    if (m < M && k < H) {
      int slot = m / B, b = m % B;
      if (s == 0) val = semb[slot * H + k];
      else        val = emb[(long long)tgt[(b * S + slot) * STEPS + (s - 1)] * H + k];
      dec[((long long)s * M + m) * H + k] = val;
    }
    u16 hi = f2bf(val);
    decH[i] = hi; decL[i] = f2bf(val - bf2f(hi));
    return;
  }
  bx -= N_DEC;
  if (bx < N_H0) {
    int i = bx * 256 + tid;
    int k = i % KP, m = i / KP;
    float val = (m < M && k < H) ? ehid[(m % B) * H + k] : 0.f;
    if (m < M && k < H) h0F[m * H + k] = val;
    u16 hi = f2bf(val);
    h0H[i] = hi; h0L[i] = f2bf(val - bf2f(hi));
    return;
  }
  bx -= N_H0;
  if (bx < N_ZP) {
    int i = bx * 256 + tid;
    int k = i % KP;
    int row = M + (i / KP) % (MP - M);
    int s = i / (KP * (MP - M));
    size_t idx = ((size_t)s * MP + row) * KP + k;
    hAllH[idx] = 0; hAllL[idx] = 0;
    return;
  }
  bx -= N_ZP;
  {
    int i = bx * 256 + tid;           // MR*16: zero ebuf cols [V,VP)
    int row = i / 16, col = V + (i % 16);
    ebuf[(size_t)row * VP + col] = 0;
  }
}

// ---------------- 64x64-tile SPLIT GEMM (gi batched, gh per step) ----------------
__global__ __launch_bounds__(256) void k_gemm64s(
    const u16* __restrict__ Ahi, const u16* __restrict__ Alo,
    const u16* __restrict__ Bmh, const u16* __restrict__ Bml,
    const float* __restrict__ bias, float* __restrict__ C,
    int Mvalid, int Nvalid, int Cstride)
{
  __shared__ u16 BsH[64 * 32], BsL[64 * 32];
  const int tid = threadIdx.x;
  const int wave = tid >> 6, lane = tid & 63;
  const int wm = wave >> 1, wn = wave & 1;
  const int n0 = blockIdx.x * 64;
  const int m0 = blockIdx.y * 64;
  const int lrow = lane & 15;
  const int c16 = lane >> 4;
  const int srow = tid >> 2;
  const int sg = (tid & 3) ^ (srow & 3);
  f32x4 acc[2][2] = {};

  const u16* aH = Ahi + (size_t)(m0 + wm * 32 + lrow) * KP + c16 * 8;
  const u16* aL = Alo + (size_t)(m0 + wm * 32 + lrow) * KP + c16 * 8;
  const u16* bHs = Bmh + (size_t)(n0 + srow) * KP + sg * 8;
  const u16* bLs = Bml + (size_t)(n0 + srow) * KP + sg * 8;
  u16* lBH = BsH + wave * 512;
  u16* lBL = BsL + wave * 512;

  for (int kk = 0; kk < KP / 32; ++kk) {
    const int kb = kk * 32;
    gload16(bHs + kb, lBH);
    gload16(bLs + kb, lBL);
    __syncthreads();
    bfrag a0h = *(const bfrag*)(aH + kb);
    bfrag a1h = *(const bfrag*)(aH + 16 * KP + kb);
    bfrag a0l = *(const bfrag*)(aL + kb);
    bfrag a1l = *(const bfrag*)(aL + 16 * KP + kb);
#pragma unroll
    for (int nn = 0; nn < 2; ++nn) {
      const int br = wn * 32 + nn * 16 + lrow;
      const int goff = br * 32 + ((c16 ^ (br & 3)) << 3);
      bfrag bh = *(const bfrag*)&BsH[goff];
      bfrag bl = *(const bfrag*)&BsL[goff];
      acc[0][nn] = __builtin_amdgcn_mfma_f32_16x16x32_bf16(a0h, bh, acc[0][nn], 0, 0, 0);
      acc[1][nn] = __builtin_amdgcn_mfma_f32_16x16x32_bf16(a1h, bh, acc[1][nn], 0, 0, 0);
      acc[0][nn] = __builtin_amdgcn_mfma_f32_16x16x32_bf16(a0h, bl, acc[0][nn], 0, 0, 0);
      acc[1][nn] = __builtin_amdgcn_mfma_f32_16x16x32_bf16(a1h, bl, acc[1][nn], 0, 0, 0);
      acc[0][nn] = __builtin_amdgcn_mfma_f32_16x16x32_bf16(a0l, bh, acc[0][nn], 0, 0, 0);
      acc[1][nn] = __builtin_amdgcn_mfma_f32_16x16x32_bf16(a1l, bh, acc[1][nn], 0, 0, 0);
    }
    __syncthreads();
  }
  const int orow = (lane >> 4) << 2, ocol = lane & 15;
#pragma unroll
  for (int am = 0; am < 2; ++am) {
#pragma unroll
    for (int nn = 0; nn < 2; ++nn) {
      const int gn = n0 + wn * 32 + nn * 16 + ocol;
      if (gn >= Nvalid) continue;
      const float badd = bias[gn];
#pragma unroll
      for (int r = 0; r < 4; ++r) {
        const int gm = m0 + wm * 32 + am * 16 + orow + r;
        if (gm < Mvalid) C[(long long)gm * Cstride + gn] = acc[am][nn][r] + badd;
      }
    }
  }
}

// ---------------- GRU cell ----------------
__global__ __launch_bounds__(512) void k_cell(const float* __restrict__ gi_s,
                                              const float* __restrict__ gh,
                                              const float* __restrict__ hprevF,
                                              float* __restrict__ hcurF,
                                              u16* __restrict__ hHc, u16* __restrict__ hLc) {
  int i = blockIdx.x * 512 + threadIdx.x;
  if (i >= M * H) return;
  int k = i % H, m = i / H;
  float ir = gi_s[m * H3 + k],         hr = gh[m * H3 + k];
  float iz = gi_s[m * H3 + H + k],     hz = gh[m * H3 + H + k];
  float in_ = gi_s[m * H3 + 2*H + k],  hn = gh[m * H3 + 2*H + k];
  float rr = sigm(ir + hr);
  float z = sigm(iz + hz);
  float n = tanhf(in_ + rr * hn);
  float hv = (1.f - z) * n + z * hprevF[i];
  hcurF[i] = hv;
  u16 hb = f2bf(hv);
  hHc[m * KP + k] = hb;
  hLc[m * KP + k] = f2bf(hv - bf2f(hb));
}

// ---------------- k_attn: MFMA attention, one block per (s,b) ----------------
struct SMatt {
  u16 P[32 * PLD];
  float partm[32][4];
  float parts[32][4];
  float rowred[32];
  float part2[32][4][4];
};

__global__ __launch_bounds__(512) void k_attn(
    const u16* __restrict__ hAllH, const u16* __restrict__ hAllL,
    const float* __restrict__ hallF,
    const u16* __restrict__ encbK, const u16* __restrict__ encT,
    const int* __restrict__ lens, const float* __restrict__ dec,
    const float* __restrict__ Wr, const float* __restrict__ br,
    const float* __restrict__ Wg, const float* __restrict__ bg,
    float* __restrict__ attnB, float* __restrict__ pgenB, float* __restrict__ out)
{
  __shared__ SMatt sm;
  const int s = blockIdx.x >> 4;
  const int b = blockIdx.x & 15;
  const int tid = threadIdx.x;
  const int wave = tid >> 6, lane = tid & 63;
  const int mt = wave & 1;
  const int wg = wave >> 1;
  const int lrow = lane & 15;
  const int c16 = lane >> 4;
  const int len = lens[b];
  const int rbase = mt * 16 + c16 * 4;

  for (int idx = tid; idx < 32 * 24; idx += 512)
    sm.P[(idx / 24) * PLD + 400 + (idx % 24)] = 0;

  f32x4 acc[7] = {};
  {
    const size_t arow = (size_t)s * MP + (size_t)(mt * 16 + lrow) * B + b;
    const u16* aHp = hAllH + arow * KP + c16 * 8;
    const u16* aLp = hAllL + arow * KP + c16 * 8;
    const u16* bBase = encbK + (size_t)b * 400 * TPAD + c16 * 8;
    for (int kk = 0; kk < 13; ++kk) {
      bfrag ah = *(const bfrag*)(aHp + kk * 32);
      bfrag al = *(const bfrag*)(aLp + kk * 32);
#pragma unroll
      for (int i = 0; i < 7; ++i) {
        const int jt = wg + 4 * i;
        if (jt < 25) {
          bfrag bv = *(const bfrag*)(bBase + (size_t)(jt * 16 + lrow) * TPAD + kk * 32);
          acc[i] = __builtin_amdgcn_mfma_f32_16x16x32_bf16(ah, bv, acc[i], 0, 0, 0);
          acc[i] = __builtin_amdgcn_mfma_f32_16x16x32_bf16(al, bv, acc[i], 0, 0, 0);
        }
      }
    }
  }

  {
    float pm[4] = {-1e30f, -1e30f, -1e30f, -1e30f};
#pragma unroll
    for (int i = 0; i < 7; ++i) {
      const int jt = wg + 4 * i;
      if (jt >= 25) continue;
      const int t = jt * 16 + lrow;
      const bool ok = t < len;
#pragma unroll
      for (int rr = 0; rr < 4; ++rr) pm[rr] = fmaxf(pm[rr], ok ? acc[i][rr] : -1e30f);
    }
#pragma unroll
    for (int d = 1; d < 16; d <<= 1) {
#pragma unroll
      for (int rr = 0; rr < 4; ++rr) pm[rr] = fmaxf(pm[rr], __shfl_xor(pm[rr], d));
    }
    if (lrow == 0) {
#pragma unroll
      for (int rr = 0; rr < 4; ++rr) sm.partm[rbase + rr][wg] = pm[rr];
    }
  }
  __syncthreads();
  if (tid < 32)
    sm.rowred[tid] = fmaxf(fmaxf(sm.partm[tid][0], sm.partm[tid][1]),
                           fmaxf(sm.partm[tid][2], sm.partm[tid][3]));
  __syncthreads();
  float Mx[4];
#pragma unroll
  for (int rr = 0; rr < 4; ++rr) Mx[rr] = sm.rowred[rbase + rr];
  {
    float ps[4] = {0.f, 0.f, 0.f, 0.f};
#pragma unroll
    for (int i = 0; i < 7; ++i) {
      const int jt = wg + 4 * i;
      if (jt >= 25) continue;
      const int t = jt * 16 + lrow;
      const bool ok = t < len;
#pragma unroll
      for (int rr = 0; rr < 4; ++rr) {
        float e = ok ? __expf(acc[i][rr] - Mx[rr]) : 0.f;
        acc[i][rr] = e;
        ps[rr] += e;
      }
    }
#pragma unroll
    for (int d = 1; d < 16; d <<= 1) {
#pragma unroll
      for (int rr = 0; rr < 4; ++rr) ps[rr] += __shfl_xor(ps[rr], d);
    }
    if (lrow == 0) {
#pragma unroll
      for (int rr = 0; rr < 4; ++rr) sm.parts[rbase + rr][wg] = ps[rr];
    }
  }
  __syncthreads();
  if (tid < 32)
    sm.rowred[tid] = sm.parts[tid][0] + sm.parts[tid][1] + sm.parts[tid][2] + sm.parts[tid][3];
  __syncthreads();
  {
    float inv[4];
#pragma unroll
    for (int rr = 0; rr < 4; ++rr) inv[rr] = 1.f / sm.rowred[rbase + rr];
#pragma unroll
    for (int i = 0; i < 7; ++i) {
      const int jt = wg + 4 * i;
      if (jt >= 25) continue;
      const int t = jt * 16 + lrow;
#pragma unroll
      for (int rr = 0; rr < 4; ++rr) {
        const int row = rbase + rr;
        const float p = acc[i][rr] * inv[rr];
        sm.P[row * PLD + t] = f2bfn(p);
        if (row < 30) attnB[((size_t)s * M + row * B + b) * T + t] = p;
      }
    }
  }
  __syncthreads();

  f32x4 acc2[7] = {};
  {
    const u16* bBase = encT + (size_t)b * 400 * TPAD + c16 * 8;
    const u16* aP = sm.P + (mt * 16 + lrow) * PLD + c16 * 8;
    for (int kk = 0; kk < 13; ++kk) {
      bfrag ap = *(const bfrag*)(aP + kk * 32);
#pragma unroll
      for (int i = 0; i < 7; ++i) {
        const int jk = wg + 4 * i;
        if (jk < 25) {
          bfrag bv = *(const bfrag*)(bBase + (size_t)(jk * 16 + lrow) * TPAD + kk * 32);
          acc2[i] = __builtin_amdgcn_mfma_f32_16x16x32_bf16(ap, bv, acc2[i], 0, 0, 0);
        }
      }
    }
  }
  {
    float pw[4] = {0.f, 0.f, 0.f, 0.f};
    float pg0[4] = {0.f, 0.f, 0.f, 0.f};
    float pg1[4] = {0.f, 0.f, 0.f, 0.f};
    float pg2[4] = {0.f, 0.f, 0.f, 0.f};
    const bool do_g = (s == 0);
#pragma unroll
    for (int i = 0; i < 7; ++i) {
      const int jk = wg + 4 * i;
      if (jk >= 25) continue;
      const int k = jk * 16 + lrow;
      const float wr = Wr[H + k];
      float w0 = 0.f, w1 = 0.f, w2 = 0.f;
      if (do_g) { w0 = Wg[k]; w1 = Wg[H + k]; w2 = Wg[2 * H + k]; }
#pragma unroll
      for (int rr = 0; rr < 4; ++rr) {
        const float v = acc2[i][rr];
        pw[rr] = fmaf(v, wr, pw[rr]);
        if (do_g) {
          pg0[rr] = fmaf(v, w0, pg0[rr]);
          pg1[rr] = fmaf(v, w1, pg1[rr]);
          pg2[rr] = fmaf(v, w2, pg2[rr]);
        }
      }
    }
#pragma unroll
    for (int d = 1; d < 16; d <<= 1) {
#pragma unroll
      for (int rr = 0; rr < 4; ++rr) {
        pw[rr] += __shfl_xor(pw[rr], d);
        pg0[rr] += __shfl_xor(pg0[rr], d);
        pg1[rr] += __shfl_xor(pg1[rr], d);
        pg2[rr] += __shfl_xor(pg2[rr], d);
      }
    }
    if (lrow == 0) {
#pragma unroll
      for (int rr = 0; rr < 4; ++rr) {
        sm.part2[rbase + rr][wg][0] = pw[rr];
        sm.part2[rbase + rr][wg][1] = pg0[rr];
        sm.part2[rbase + rr][wg][2] = pg1[rr];
        sm.part2[rbase + rr][wg][3] = pg2[rr];
      }
    }
  }
  __syncthreads();

  if (tid < 480) {
    const int row = tid >> 4;
    const int l16 = tid & 15;
    const int m = row * B + b;
    const float* hF = hallF + ((size_t)s * M + m) * H;
    const float* dF = dec + ((size_t)s * M + m) * H;
    float p = 0.f;
    for (int j = 0; j < 25; ++j) {
      const int k = l16 + 16 * j;
      p += hF[k] * Wr[k] + dF[k] * Wr[2 * H + k];
    }
#pragma unroll
    for (int d = 1; d < 16; d <<= 1) p += __shfl_xor(p, d);
    if (l16 == 0) {
      float cw = sm.part2[row][0][0] + sm.part2[row][1][0] +
                 sm.part2[row][2][0] + sm.part2[row][3][0];
      pgenB[s * M + m] = sigm(p + cw + br[0]);
    }
    if (s == 0 && l16 < NG) {
      float gv = sm.part2[row][0][1 + l16] + sm.part2[row][1][1 + l16] +
                 sm.part2[row][2][1 + l16] + sm.part2[row][3][1 + l16];
      out[PTS + (long long)m * NG + l16] = gv + bg[l16];
    }
  }
}

// ---------------- k_vocab: 256x128 tiles, BK=64 per barrier-pair (2 sub-tiles), exp-direct ----------------
// Sub-buffer layout/swizzle byte-identical to R10's proven 128x32 staging.
__global__ __launch_bounds__(512) void k_vocab(
    const u16* __restrict__ hAllH, const u16* __restrict__ ebf,
    u16* __restrict__ ebuf)
{
  __shared__ u16 Bs[4][4096];     // [dbuf*2+sub][128 rows x 32 k]
  const int bx = blockIdx.x;
  const int tid = threadIdx.x;
  const int wave = tid >> 6, lane = tid & 63;
  const int bxs = (bx & 7) * (NVB / 8) + (bx >> 3);   // bijective XCD swizzle
  const int nb = bxs / NMP;
  const int mp = bxs % NMP;
  const int n0 = nb * 128;
  const int m0 = mp * 256;
  const int wm = wave >> 1, wn = wave & 1;
  const int lrow = lane & 15;
  const int c16 = lane >> 4;
  const int srow = tid >> 2;
  const int sg = (tid & 3) ^ (srow & 3);
  f32x4 acc[4][4] = {};

  const u16* aBase = hAllH + (size_t)(m0 + wm * 64 + lrow) * KP + c16 * 8;
  const u16* bS = ebf + (size_t)(n0 + srow) * KP + sg * 8;

  // prologue: stage sub-tiles k=0 and k=32 into dbuf 0
  gload16(bS + 0,  &Bs[0][wave * 512]);
  gload16(bS + 32, &Bs[1][wave * 512]);
  int cur = 0;
#pragma unroll 1
  for (int p = 0; p < 7; ++p) {         // 6 full BK=64 phases + 1 BK=32 tail (13*32=416)
    const int kb = p * 64;
    // A-frags for this phase (4 or 8 global_load_dwordx4)
    bfrag a[4][2];
#pragma unroll
    for (int r = 0; r < 4; ++r) {
      a[r][0] = *(const bfrag*)(aBase + r * 16 * KP + kb);
      if (p < 6) a[r][1] = *(const bfrag*)(aBase + r * 16 * KP + kb + 32);
    }
    if (p < 5) {
      gload16(bS + kb + 64, &Bs[(cur ^ 1) * 2 + 0][wave * 512]);
      gload16(bS + kb + 96, &Bs[(cur ^ 1) * 2 + 1][wave * 512]);
      // outstanding: cur(2,oldest) + A(8) + next(2) = 12 -> force the 2 oldest
      asm volatile("s_waitcnt vmcnt(10)" ::: "memory");
    } else if (p == 5) {
      gload16(bS + kb + 64, &Bs[(cur ^ 1) * 2 + 0][wave * 512]);  // tail sub-tile k=384
      // outstanding: cur(2) + A(8) + next(1) = 11 -> force the 2 oldest
      asm volatile("s_waitcnt vmcnt(9)" ::: "memory");
    } else {
      // outstanding: cur(1) + A(4) = 5 -> force the 1 oldest
      asm volatile("s_waitcnt vmcnt(4)" ::: "memory");
    }
    __builtin_amdgcn_sched_barrier(0);
    __builtin_amdgcn_s_barrier();       // staged sub-tiles of dbuf 'cur' ready
    {
      const u16* Bb = Bs[cur * 2 + 0];
      bfrag bfv[4];
#pragma unroll
      for (int nn = 0; nn < 4; ++nn) {
        const int brr = wn * 64 + nn * 16 + lrow;
        bfv[nn] = *(const bfrag*)&Bb[brr * 32 + ((c16 ^ (brr & 3)) << 3)];
      }
#pragma unroll
      for (int nn = 0; nn < 4; ++nn) {
#pragma unroll
        for (int r = 0; r < 4; ++r)
          acc[r][nn] = __builtin_amdgcn_mfma_f32_16x16x32_bf16(a[r][0], bfv[nn], acc[r][nn], 0, 0, 0);
      }
    }
    if (p < 6) {
      const u16* Bb = Bs[cur * 2 + 1];
      bfrag bfv[4];
#pragma unroll
      for (int nn = 0; nn < 4; ++nn) {
        const int brr = wn * 64 + nn * 16 + lrow;
        bfv[nn] = *(const bfrag*)&Bb[brr * 32 + ((c16 ^ (brr & 3)) << 3)];
      }
#pragma unroll
      for (int nn = 0; nn < 4; ++nn) {
#pragma unroll
        for (int r = 0; r < 4; ++r)
          acc[r][nn] = __builtin_amdgcn_mfma_f32_16x16x32_bf16(a[r][1], bfv[nn], acc[r][nn], 0, 0, 0);
      }
    }
    __builtin_amdgcn_sched_barrier(0);
    __builtin_amdgcn_s_barrier();       // all waves done reading dbuf 'cur'
    __builtin_amdgcn_sched_barrier(0);
    cur ^= 1;
  }

  // epilogue: e = exp(logit) -> bf16 (scale/normalize applied in k_merge)
  const int orow = (lane >> 4) << 2, ocol = lane & 15;
#pragma unroll
  for (int af = 0; af < 4; ++af) {
#pragma unroll
    for (int r = 0; r < 4; ++r) {
      const int rl = wm * 64 + af * 16 + orow + r;
      const size_t R = (size_t)m0 + rl;
      if ((R % MP) >= M) continue;                 // pad row
#pragma unroll
      for (int nn = 0; nn < 4; ++nn) {
        const int gn = n0 + wn * 64 + nn * 16 + ocol;
        if (gn < V) ebuf[R * VP + gn] = f2bfn(__expf(acc[af][nn][r]));
      }
    }
  }
}

// ---------------- k_merge: row-sum from ebuf, scale, write, scatter ----------------
__global__ __launch_bounds__(512) void k_merge(
    const u16* __restrict__ ebuf, const float* __restrict__ pgenB,
    const float* __restrict__ attnB, const int* __restrict__ story,
    float* __restrict__ out)
{
  const int bxi = blockIdx.x;
  const int s = bxi / M, m = bxi % M, b = m % B;
  const size_t R = (size_t)s * MP + m;
  const int tid = threadIdx.x;
  const int wave = tid >> 6, lane = tid & 63;
  __shared__ float red8[8];
  const u16* erow = ebuf + R * VP;
  bfrag ch[6];
  float sum = 0.f;
#pragma unroll
  for (int j = 0; j < 6; ++j) {
    const int c = j * 512 + tid;
    if (c < VP / 8) {
      ch[j] = *(const bfrag*)(erow + (size_t)c * 8);
#pragma unroll
      for (int e = 0; e < 8; ++e) sum += bf2f((u16)ch[j][e]);
    }
  }
#pragma unroll
  for (int off = 32; off; off >>= 1) sum += __shfl_xor(sum, off);
  if (lane == 0) red8[wave] = sum;
  __syncthreads();
  float Sv = 0.f;
#pragma unroll
  for (int j = 0; j < 8; ++j) Sv += red8[j];
  const float pg = pgenB[s * M + m];
  const float scale = pg / Sv;
  float* orow = out + ((size_t)m * STEPS + s) * V;
#pragma unroll
  for (int j = 0; j < 6; ++j) {
    const int c = j * 512 + tid;
    if (c < V / 8) {
      f32x4 w0, w1;
#pragma unroll
      for (int e = 0; e < 4; ++e) {
        w0[e] = bf2f((u16)ch[j][e]) * scale;
        w1[e] = bf2f((u16)ch[j][4 + e]) * scale;
      }
      *(f32x4*)(orow + (size_t)c * 8) = w0;
      *(f32x4*)(orow + (size_t)c * 8 + 4) = w1;
    }
  }
  __syncthreads();
  const float om = 1.f - pg;
  for (int t = tid; t < T; t += 512) {
    float a = attnB[((size_t)s * M + m) * T + t];
    if (a != 0.f) atomicAdd(orow + story[b * T + t], om * a);
  }
}

// ---------------- launch ----------------

extern "C" void kernel_launch(void* const* d_in, const int* in_sizes, int n_in,
                              void* d_out, int out_size, void* d_ws, size_t ws_size,
                              hipStream_t stream) {
  (void)in_sizes; (void)n_in; (void)out_size; (void)ws_size;
  const float* emb  = (const float*)d_in[0];
  const float* Wih  = (const float*)d_in[1];
  const float* Whh  = (const float*)d_in[2];
  const float* bih  = (const float*)d_in[3];
  const float* bhh  = (const float*)d_in[4];
  const float* Wr   = (const float*)d_in[5];
  const float* br   = (const float*)d_in[6];
  const float* Wg   = (const float*)d_in[7];
  const float* bg   = (const float*)d_in[8];
  const float* semb = (const float*)d_in[9];
  const float* ehid = (const float*)d_in[10];
  const float* enc  = (const float*)d_in[11];
  const int*   lens = (const int*)d_in[12];
  const int*   story= (const int*)d_in[13];
  const int*   tgt  = (const int*)d_in[14];
  float* out = (float*)d_out;

  char* w = (char*)d_ws;
  size_t off = 0;
  auto alloc = [&](size_t n) -> void* {
    void* p = w + off;
    off = (off + n + 255) & ~(size_t)255;
    return p;
  };
  u16* ebf    = (u16*)alloc((size_t)VP * KP * 2);
  u16* wihH   = (u16*)alloc((size_t)NWP * KP * 2);
  u16* wihL   = (u16*)alloc((size_t)NWP * KP * 2);
  u16* whhH   = (u16*)alloc((size_t)NWP * KP * 2);
  u16* whhL   = (u16*)alloc((size_t)NWP * KP * 2);
  u16* decH   = (u16*)alloc((size_t)STEPS * MP * KP * 2);
  u16* decL   = (u16*)alloc((size_t)STEPS * MP * KP * 2);
  float* dec  = (float*)alloc((size_t)STEPS * M * H * 4);
  float* h0F  = (float*)alloc((size_t)M * H * 4);
  u16* h0H    = (u16*)alloc((size_t)MP * KP * 2);
  u16* h0L    = (u16*)alloc((size_t)MP * KP * 2);
  u16* hAllH  = (u16*)alloc((size_t)MR * KP * 2);
  u16* hAllL  = (u16*)alloc((size_t)MR * KP * 2);
  float* hallF= (float*)alloc((size_t)STEPS * M * H * 4);
  float* gi   = (float*)alloc((size_t)MR * H3 * 4);
  float* gh   = (float*)alloc((size_t)M * H3 * 4);
  float* attnB= (float*)alloc((size_t)STEPS * M * T * 4);
  float* pgenB= (float*)alloc((size_t)STEPS * M * 4);
  u16* ebuf   = (u16*)alloc((size_t)MR * VP * 2);
  u16* encbK  = (u16*)alloc((size_t)B * 400 * TPAD * 2);
  u16* encT   = (u16*)alloc((size_t)B * 400 * TPAD * 2);

  k_init<<<N_INIT, 256, 0, stream>>>(emb, enc, Wih, Whh, semb, ehid, tgt,
      ebf, encbK, encT, wihH, wihL, whhH, whhL, dec, decH, decL,
      h0F, h0H, h0L, hAllH, hAllL, ebuf);
  // all-steps gi = dec @ Wih^T + bih
  k_gemm64s<<<dim3((H3 + 63) / 64, MR / 64), 256, 0, stream>>>(
      decH, decL, wihH, wihL, bih, gi, MR, H3, H3);

  // serial GRU spine: gh GEMM + cell per step
  for (int s = 0; s < STEPS; ++s) {
    const u16* pH = (s == 0) ? h0H : hAllH + (size_t)(s - 1) * MP * KP;
    const u16* pL = (s == 0) ? h0L : hAllL + (size_t)(s - 1) * MP * KP;
    const float* pF = (s == 0) ? h0F : hallF + (size_t)(s - 1) * M * H;
    k_gemm64s<<<dim3((H3 + 63) / 64, (M + 63) / 64), 256, 0, stream>>>(
        pH, pL, whhH, whhL, bhh, gh, M, H3, H3);
    k_cell<<<(M * H + 511) / 512, 512, 0, stream>>>(
        gi + (size_t)s * MP * H3, gh, pF,
        hallF + (size_t)s * M * H,
        hAllH + (size_t)s * MP * KP, hAllL + (size_t)s * MP * KP);
  }

  // batched parallel phase
  k_vocab<<<NVB, 512, 0, stream>>>(hAllH, ebf, ebuf);
  k_attn<<<STEPS * B, 512, 0, stream>>>(hAllH, hAllL, hallF, encbK, encT, lens,
                                        dec, Wr, br, Wg, bg, attnB, pgenB, out);
  k_merge<<<STEPS * M, 512, 0, stream>>>(ebuf, pgenB, attnB, story, out);
}

// Round 12
// 554.479 us; speedup vs baseline: 1.3156x; 1.0913x over previous
//
#include <hip/hip_runtime.h>
#include <hip/hip_bf16.h>

#define DEV __device__ __forceinline__

constexpr int B = 16, T = 400, H = 400, V = 22000, S = 30, STEPS = 8, NG = 3;
constexpr int M  = S * B;      // 480
constexpr int H3 = 3 * H;      // 1200
constexpr int KP = 416;        // K padded to 13*32
constexpr int VP = 22016;      // V padded to 172*128
constexpr int MP = 512;        // M padded (per step slot)
constexpr int MR = STEPS * MP; // 4096
constexpr int NWP = 1280;
constexpr int NBLK = VP / 128; // 172
constexpr int NMP = MR / 256;  // 16
constexpr int NVB = NBLK * NMP;// 2752
constexpr int NVB_S = NBLK * 2;                    // 344 per-step vocab blocks (8 | 344)
constexpr int NCT = (H3 + 63) / 64;                // 19 gh col-tiles
constexpr int NGH = NCT * ((M + 63) / 64);         // 152 gh blocks
constexpr int TPAD = 416;
constexpr int PLD = 424;
constexpr long long PTS = (long long)S * B * STEPS * V;

typedef __attribute__((ext_vector_type(8))) short bfrag;
typedef __attribute__((ext_vector_type(4))) float f32x4;
typedef unsigned short u16;

DEV u16 f2bf(float x) {                 // manual RNE (init/split paths)
  unsigned u = __float_as_uint(x);
  u += 0x7FFFu + ((u >> 16) & 1u);
  return (u16)(u >> 16);
}
DEV u16 f2bfn(float x) {                // native cvt (hot paths)
  __hip_bfloat16 h = __float2bfloat16(x);
  union { __hip_bfloat16 b; u16 u; } cv; cv.b = h; return cv.u;
}
DEV float bf2f(u16 h) { return __uint_as_float(((unsigned)h) << 16); }
DEV float sigm(float x) { return 1.0f / (1.0f + __expf(-x)); }

DEV void gload16(const u16* g, u16* l) {
  __builtin_amdgcn_global_load_lds(
      (const __attribute__((address_space(1))) void*)g,
      (__attribute__((address_space(3))) void*)l, 16, 0, 0);
}

// ---------------- merged init (KP=416) ----------------
constexpr int N_EMB = VP * KP / 256;               // 35776
constexpr int N_ENC = B * 400 * TPAD / 256;        // 10400
constexpr int N_W   = NWP * KP / 256;              // 2080
constexpr int N_DEC = STEPS * MP * KP / 256;       // 6656
constexpr int N_H0  = MP * KP / 256;               // 832
constexpr int N_ZP  = STEPS * (MP - M) * KP / 256; // 416
constexpr int N_ZE  = MR * 16 / 256;               // 256
constexpr int N_INIT = N_EMB + N_ENC + N_W + N_DEC + N_H0 + N_ZP + N_ZE;

__global__ __launch_bounds__(256) void k_init(
    const float* __restrict__ emb, const float* __restrict__ enc,
    const float* __restrict__ Wih, const float* __restrict__ Whh,
    const float* __restrict__ semb, const float* __restrict__ ehid,
    const int* __restrict__ tgt,
    u16* __restrict__ ebf, u16* __restrict__ encbK, u16* __restrict__ encT,
    u16* __restrict__ wihH, u16* __restrict__ wihL,
    u16* __restrict__ whhH, u16* __restrict__ whhL,
    float* __restrict__ dec, u16* __restrict__ decH, u16* __restrict__ decL,
    float* __restrict__ h0F, u16* __restrict__ h0H, u16* __restrict__ h0L,
    u16* __restrict__ hAllH, u16* __restrict__ hAllL, u16* __restrict__ ebuf)
{
  int bx = blockIdx.x;
  const int tid = threadIdx.x;
  if (bx < N_EMB) {
    int i = bx * 256 + tid;
    int v = i / KP, k = i % KP;
    ebf[i] = f2bf((v < V && k < H) ? emb[(long long)v * H + k] : 0.f);
    return;
  }
  bx -= N_EMB;
  if (bx < N_ENC) {
    int i = bx * 256 + tid;
    int c = i % TPAD, r = (i / TPAD) % 400, b = i / (TPAD * 400);
    encbK[i] = f2bf((c < H) ? enc[((size_t)b * T + r) * H + c] : 0.f);
    encT[i]  = f2bf((c < T) ? enc[((size_t)b * T + c) * H + r] : 0.f);
    return;
  }
  bx -= N_ENC;
  if (bx < N_W) {
    int i = bx * 256 + tid;
    int n = i / KP, k = i % KP;
    float v1 = (n < H3 && k < H) ? Wih[n * H + k] : 0.f;
    u16 h1 = f2bf(v1);
    wihH[i] = h1; wihL[i] = f2bf(v1 - bf2f(h1));
    float v2 = (n < H3 && k < H) ? Whh[n * H + k] : 0.f;
    u16 h2 = f2bf(v2);
    whhH[i] = h2; whhL[i] = f2bf(v2 - bf2f(h2));
    return;
  }
  bx -= N_W;
  if (bx < N_DEC) {
    int i = bx * 256 + tid;
    int k = i % KP, m = (i / KP) % MP, s = i / (KP * MP);
    float val = 0.f;
    if (m < M && k < H) {
      int slot = m / B, b = m % B;
      if (s == 0) val = semb[slot * H + k];
      else        val = emb[(long long)tgt[(b * S + slot) * STEPS + (s - 1)] * H + k];
      dec[((long long)s * M + m) * H + k] = val;
    }
    u16 hi = f2bf(val);
    decH[i] = hi; decL[i] = f2bf(val - bf2f(hi));
    return;
  }
  bx -= N_DEC;
  if (bx < N_H0) {
    int i = bx * 256 + tid;
    int k = i % KP, m = i / KP;
    float val = (m < M && k < H) ? ehid[(m % B) * H + k] : 0.f;
    if (m < M && k < H) h0F[m * H + k] = val;
    u16 hi = f2bf(val);
    h0H[i] = hi; h0L[i] = f2bf(val - bf2f(hi));
    return;
  }
  bx -= N_H0;
  if (bx < N_ZP) {
    int i = bx * 256 + tid;
    int k = i % KP;
    int row = M + (i / KP) % (MP - M);
    int s = i / (KP * (MP - M));
    size_t idx = ((size_t)s * MP + row) * KP + k;
    hAllH[idx] = 0; hAllL[idx] = 0;
    return;
  }
  bx -= N_ZP;
  {
    int i = bx * 256 + tid;           // MR*16: zero ebuf cols [V,VP)
    int row = i / 16, col = V + (i % 16);
    ebuf[(size_t)row * VP + col] = 0;
  }
}

// ---------------- 64x64-tile SPLIT GEMM (gi batched, gh step 0) ----------------
__global__ __launch_bounds__(256) void k_gemm64s(
    const u16* __restrict__ Ahi, const u16* __restrict__ Alo,
    const u16* __restrict__ Bmh, const u16* __restrict__ Bml,
    const float* __restrict__ bias, float* __restrict__ C,
    int Mvalid, int Nvalid, int Cstride)
{
  __shared__ u16 BsH[64 * 32], BsL[64 * 32];
  const int tid = threadIdx.x;
  const int wave = tid >> 6, lane = tid & 63;
  const int wm = wave >> 1, wn = wave & 1;
  const int n0 = blockIdx.x * 64;
  const int m0 = blockIdx.y * 64;
  const int lrow = lane & 15;
  const int c16 = lane >> 4;
  const int srow = tid >> 2;
  const int sg = (tid & 3) ^ (srow & 3);
  f32x4 acc[2][2] = {};

  const u16* aH = Ahi + (size_t)(m0 + wm * 32 + lrow) * KP + c16 * 8;
  const u16* aL = Alo + (size_t)(m0 + wm * 32 + lrow) * KP + c16 * 8;
  const u16* bHs = Bmh + (size_t)(n0 + srow) * KP + sg * 8;
  const u16* bLs = Bml + (size_t)(n0 + srow) * KP + sg * 8;
  u16* lBH = BsH + wave * 512;
  u16* lBL = BsL + wave * 512;

  for (int kk = 0; kk < KP / 32; ++kk) {
    const int kb = kk * 32;
    gload16(bHs + kb, lBH);
    gload16(bLs + kb, lBL);
    __syncthreads();
    bfrag a0h = *(const bfrag*)(aH + kb);
    bfrag a1h = *(const bfrag*)(aH + 16 * KP + kb);
    bfrag a0l = *(const bfrag*)(aL + kb);
    bfrag a1l = *(const bfrag*)(aL + 16 * KP + kb);
#pragma unroll
    for (int nn = 0; nn < 2; ++nn) {
      const int br = wn * 32 + nn * 16 + lrow;
      const int goff = br * 32 + ((c16 ^ (br & 3)) << 3);
      bfrag bh = *(const bfrag*)&BsH[goff];
      bfrag bl = *(const bfrag*)&BsL[goff];
      acc[0][nn] = __builtin_amdgcn_mfma_f32_16x16x32_bf16(a0h, bh, acc[0][nn], 0, 0, 0);
      acc[1][nn] = __builtin_amdgcn_mfma_f32_16x16x32_bf16(a1h, bh, acc[1][nn], 0, 0, 0);
      acc[0][nn] = __builtin_amdgcn_mfma_f32_16x16x32_bf16(a0h, bl, acc[0][nn], 0, 0, 0);
      acc[1][nn] = __builtin_amdgcn_mfma_f32_16x16x32_bf16(a1h, bl, acc[1][nn], 0, 0, 0);
      acc[0][nn] = __builtin_amdgcn_mfma_f32_16x16x32_bf16(a0l, bh, acc[0][nn], 0, 0, 0);
      acc[1][nn] = __builtin_amdgcn_mfma_f32_16x16x32_bf16(a1l, bh, acc[1][nn], 0, 0, 0);
    }
    __syncthreads();
  }
  const int orow = (lane >> 4) << 2, ocol = lane & 15;
#pragma unroll
  for (int am = 0; am < 2; ++am) {
#pragma unroll
    for (int nn = 0; nn < 2; ++nn) {
      const int gn = n0 + wn * 32 + nn * 16 + ocol;
      if (gn >= Nvalid) continue;
      const float badd = bias[gn];
#pragma unroll
      for (int r = 0; r < 4; ++r) {
        const int gm = m0 + wm * 32 + am * 16 + orow + r;
        if (gm < Mvalid) C[(long long)gm * Cstride + gn] = acc[am][nn][r] + badd;
      }
    }
  }
}

// ---------------- GRU cell ----------------
__global__ __launch_bounds__(512) void k_cell(const float* __restrict__ gi_s,
                                              const float* __restrict__ gh,
                                              const float* __restrict__ hprevF,
                                              float* __restrict__ hcurF,
                                              u16* __restrict__ hHc, u16* __restrict__ hLc) {
  int i = blockIdx.x * 512 + threadIdx.x;
  if (i >= M * H) return;
  int k = i % H, m = i / H;
  float ir = gi_s[m * H3 + k],         hr = gh[m * H3 + k];
  float iz = gi_s[m * H3 + H + k],     hz = gh[m * H3 + H + k];
  float in_ = gi_s[m * H3 + 2*H + k],  hn = gh[m * H3 + 2*H + k];
  float rr = sigm(ir + hr);
  float z = sigm(iz + hz);
  float n = tanhf(in_ + rr * hn);
  float hv = (1.f - z) * n + z * hprevF[i];
  hcurF[i] = hv;
  u16 hb = f2bf(hv);
  hHc[m * KP + k] = hb;
  hLc[m * KP + k] = f2bf(hv - bf2f(hb));
}

// ---------------- k_bigv: [vocab(step prev, 344 blocks) ∥ gh GEMM(next, 152 blocks)] ----------------
// Both branch bodies verbatim from R11-proven kernels. hPrev* serves BOTH branches
// (vocab A-panel and gh A-panel are the same h slice).
__global__ __launch_bounds__(512) void k_bigv(
    const u16* __restrict__ hPrevH, const u16* __restrict__ hPrevL,
    const u16* __restrict__ ebf, u16* __restrict__ ebuf, long long Rbase,
    const u16* __restrict__ whhH, const u16* __restrict__ whhL,
    const float* __restrict__ bhh, float* __restrict__ gh)
{
  __shared__ union SMU {
    u16 vb[4][4096];                            // vocab: [dbuf*2+sub][128 x 32]
    struct { u16 bh[64 * 32]; u16 bl[64 * 32]; } g;  // gh staging
  } sm;
  const int bx = blockIdx.x;
  const int tid = threadIdx.x;
  const int wave = tid >> 6, lane = tid & 63;

  if (bx < NVB_S) {
    // ================= vocab branch (R11 BK=64 pipeline) =================
    const int bxs = (bx & 7) * (NVB_S / 8) + (bx >> 3);   // bijective XCD swizzle
    const int nb = bxs >> 1;
    const int m0 = (bxs & 1) * 256;
    const int n0 = nb * 128;
    const int wm = wave >> 1, wn = wave & 1;
    const int lrow = lane & 15;
    const int c16 = lane >> 4;
    const int srow = tid >> 2;
    const int sg = (tid & 3) ^ (srow & 3);
    f32x4 acc[4][4] = {};

    const u16* aBase = hPrevH + (size_t)(m0 + wm * 64 + lrow) * KP + c16 * 8;
    const u16* bS = ebf + (size_t)(n0 + srow) * KP + sg * 8;

    gload16(bS + 0,  &sm.vb[0][wave * 512]);
    gload16(bS + 32, &sm.vb[1][wave * 512]);
    int cur = 0;
#pragma unroll 1
    for (int p = 0; p < 7; ++p) {       // 6 full BK=64 phases + 1 BK=32 tail
      const int kb = p * 64;
      bfrag a[4][2];
#pragma unroll
      for (int r = 0; r < 4; ++r) {
        a[r][0] = *(const bfrag*)(aBase + r * 16 * KP + kb);
        if (p < 6) a[r][1] = *(const bfrag*)(aBase + r * 16 * KP + kb + 32);
      }
      if (p < 5) {
        gload16(bS + kb + 64, &sm.vb[(cur ^ 1) * 2 + 0][wave * 512]);
        gload16(bS + kb + 96, &sm.vb[(cur ^ 1) * 2 + 1][wave * 512]);
        asm volatile("s_waitcnt vmcnt(10)" ::: "memory");
      } else if (p == 5) {
        gload16(bS + kb + 64, &sm.vb[(cur ^ 1) * 2 + 0][wave * 512]);
        asm volatile("s_waitcnt vmcnt(9)" ::: "memory");
      } else {
        asm volatile("s_waitcnt vmcnt(4)" ::: "memory");
      }
      __builtin_amdgcn_sched_barrier(0);
      __builtin_amdgcn_s_barrier();
      {
        const u16* Bb = sm.vb[cur * 2 + 0];
        bfrag bfv[4];
#pragma unroll
        for (int nn = 0; nn < 4; ++nn) {
          const int brr = wn * 64 + nn * 16 + lrow;
          bfv[nn] = *(const bfrag*)&Bb[brr * 32 + ((c16 ^ (brr & 3)) << 3)];
        }
#pragma unroll
        for (int nn = 0; nn < 4; ++nn) {
#pragma unroll
          for (int r = 0; r < 4; ++r)
            acc[r][nn] = __builtin_amdgcn_mfma_f32_16x16x32_bf16(a[r][0], bfv[nn], acc[r][nn], 0, 0, 0);
        }
      }
      if (p < 6) {
        const u16* Bb = sm.vb[cur * 2 + 1];
        bfrag bfv[4];
#pragma unroll
        for (int nn = 0; nn < 4; ++nn) {
          const int brr = wn * 64 + nn * 16 + lrow;
          bfv[nn] = *(const bfrag*)&Bb[brr * 32 + ((c16 ^ (brr & 3)) << 3)];
        }
#pragma unroll
        for (int nn = 0; nn < 4; ++nn) {
#pragma unroll
          for (int r = 0; r < 4; ++r)
            acc[r][nn] = __builtin_amdgcn_mfma_f32_16x16x32_bf16(a[r][1], bfv[nn], acc[r][nn], 0, 0, 0);
        }
      }
      __builtin_amdgcn_sched_barrier(0);
      __builtin_amdgcn_s_barrier();
      __builtin_amdgcn_sched_barrier(0);
      cur ^= 1;
    }

    // epilogue: e = exp(logit) -> bf16 (normalized in k_merge)
    const int orow = (lane >> 4) << 2, ocol = lane & 15;
#pragma unroll
    for (int af = 0; af < 4; ++af) {
#pragma unroll
      for (int r = 0; r < 4; ++r) {
        const int rl = m0 + wm * 64 + af * 16 + orow + r;   // local row 0..511
        if (rl >= M) continue;                              // pad rows 480..511
        const size_t R = (size_t)(Rbase + rl);
#pragma unroll
        for (int nn = 0; nn < 4; ++nn) {
          const int gn = n0 + wn * 64 + nn * 16 + ocol;
          if (gn < V) ebuf[R * VP + gn] = f2bfn(__expf(acc[af][nn][r]));
        }
      }
    }
  } else {
    // ================= gh GEMM branch (threads <256 active; uniform barriers) =================
    const int gb = bx - NVB_S;
    const int n0 = (gb % NCT) * 64;
    const int m0 = (gb / NCT) * 64;
    const bool act = tid < 256;
    const int wm = wave >> 1, wn = wave & 1;
    const int lrow = lane & 15;
    const int c16 = lane >> 4;
    const int srow = tid >> 2;
    const int sg = (tid & 3) ^ (srow & 3);
    f32x4 acc[2][2] = {};

    const u16* aH = hPrevH + (size_t)(m0 + (wm & 1) * 32 + lrow) * KP + c16 * 8;
    const u16* aL = hPrevL + (size_t)(m0 + (wm & 1) * 32 + lrow) * KP + c16 * 8;
    const u16* bHs = whhH + (size_t)(n0 + (srow & 63)) * KP + sg * 8;
    const u16* bLs = whhL + (size_t)(n0 + (srow & 63)) * KP + sg * 8;
    u16* lBH = sm.g.bh + (wave & 3) * 512;
    u16* lBL = sm.g.bl + (wave & 3) * 512;

    for (int kk = 0; kk < KP / 32; ++kk) {
      const int kb = kk * 32;
      if (act) {
        gload16(bHs + kb, lBH);
        gload16(bLs + kb, lBL);
      }
      __syncthreads();
      if (act) {
        bfrag a0h = *(const bfrag*)(aH + kb);
        bfrag a1h = *(const bfrag*)(aH + 16 * KP + kb);
        bfrag a0l = *(const bfrag*)(aL + kb);
        bfrag a1l = *(const bfrag*)(aL + 16 * KP + kb);
#pragma unroll
        for (int nn = 0; nn < 2; ++nn) {
          const int br = wn * 32 + nn * 16 + lrow;
          const int goff = br * 32 + ((c16 ^ (br & 3)) << 3);
          bfrag bh = *(const bfrag*)&sm.g.bh[goff];
          bfrag bl = *(const bfrag*)&sm.g.bl[goff];
          acc[0][nn] = __builtin_amdgcn_mfma_f32_16x16x32_bf16(a0h, bh, acc[0][nn], 0, 0, 0);
          acc[1][nn] = __builtin_amdgcn_mfma_f32_16x16x32_bf16(a1h, bh, acc[1][nn], 0, 0, 0);
          acc[0][nn] = __builtin_amdgcn_mfma_f32_16x16x32_bf16(a0h, bl, acc[0][nn], 0, 0, 0);
          acc[1][nn] = __builtin_amdgcn_mfma_f32_16x16x32_bf16(a1h, bl, acc[1][nn], 0, 0, 0);
          acc[0][nn] = __builtin_amdgcn_mfma_f32_16x16x32_bf16(a0l, bh, acc[0][nn], 0, 0, 0);
          acc[1][nn] = __builtin_amdgcn_mfma_f32_16x16x32_bf16(a1l, bh, acc[1][nn], 0, 0, 0);
        }
      }
      __syncthreads();
    }
    if (act) {
      const int orow = (lane >> 4) << 2, ocol = lane & 15;
#pragma unroll
      for (int am = 0; am < 2; ++am) {
#pragma unroll
        for (int nn = 0; nn < 2; ++nn) {
          const int gn = n0 + wn * 32 + nn * 16 + ocol;
          if (gn >= H3) continue;
          const float badd = bhh[gn];
#pragma unroll
          for (int r = 0; r < 4; ++r) {
            const int gm = m0 + wm * 32 + am * 16 + orow + r;
            if (gm < M) gh[(long long)gm * H3 + gn] = acc[am][nn][r] + badd;
          }
        }
      }
    }
  }
}

// ---------------- k_attn: MFMA attention, one block per (s,b) ----------------
struct SMatt {
  u16 P[32 * PLD];
  float partm[32][4];
  float parts[32][4];
  float rowred[32];
  float part2[32][4][4];
};

__global__ __launch_bounds__(512) void k_attn(
    const u16* __restrict__ hAllH, const u16* __restrict__ hAllL,
    const float* __restrict__ hallF,
    const u16* __restrict__ encbK, const u16* __restrict__ encT,
    const int* __restrict__ lens, const float* __restrict__ dec,
    const float* __restrict__ Wr, const float* __restrict__ br,
    const float* __restrict__ Wg, const float* __restrict__ bg,
    float* __restrict__ attnB, float* __restrict__ pgenB, float* __restrict__ out)
{
  __shared__ SMatt sm;
  const int s = blockIdx.x >> 4;
  const int b = blockIdx.x & 15;
  const int tid = threadIdx.x;
  const int wave = tid >> 6, lane = tid & 63;
  const int mt = wave & 1;
  const int wg = wave >> 1;
  const int lrow = lane & 15;
  const int c16 = lane >> 4;
  const int len = lens[b];
  const int rbase = mt * 16 + c16 * 4;

  for (int idx = tid; idx < 32 * 24; idx += 512)
    sm.P[(idx / 24) * PLD + 400 + (idx % 24)] = 0;

  f32x4 acc[7] = {};
  {
    const size_t arow = (size_t)s * MP + (size_t)(mt * 16 + lrow) * B + b;
    const u16* aHp = hAllH + arow * KP + c16 * 8;
    const u16* aLp = hAllL + arow * KP + c16 * 8;
    const u16* bBase = encbK + (size_t)b * 400 * TPAD + c16 * 8;
    for (int kk = 0; kk < 13; ++kk) {
      bfrag ah = *(const bfrag*)(aHp + kk * 32);
      bfrag al = *(const bfrag*)(aLp + kk * 32);
#pragma unroll
      for (int i = 0; i < 7; ++i) {
        const int jt = wg + 4 * i;
        if (jt < 25) {
          bfrag bv = *(const bfrag*)(bBase + (size_t)(jt * 16 + lrow) * TPAD + kk * 32);
          acc[i] = __builtin_amdgcn_mfma_f32_16x16x32_bf16(ah, bv, acc[i], 0, 0, 0);
          acc[i] = __builtin_amdgcn_mfma_f32_16x16x32_bf16(al, bv, acc[i], 0, 0, 0);
        }
      }
    }
  }

  {
    float pm[4] = {-1e30f, -1e30f, -1e30f, -1e30f};
#pragma unroll
    for (int i = 0; i < 7; ++i) {
      const int jt = wg + 4 * i;
      if (jt >= 25) continue;
      const int t = jt * 16 + lrow;
      const bool ok = t < len;
#pragma unroll
      for (int rr = 0; rr < 4; ++rr) pm[rr] = fmaxf(pm[rr], ok ? acc[i][rr] : -1e30f);
    }
#pragma unroll
    for (int d = 1; d < 16; d <<= 1) {
#pragma unroll
      for (int rr = 0; rr < 4; ++rr) pm[rr] = fmaxf(pm[rr], __shfl_xor(pm[rr], d));
    }
    if (lrow == 0) {
#pragma unroll
      for (int rr = 0; rr < 4; ++rr) sm.partm[rbase + rr][wg] = pm[rr];
    }
  }
  __syncthreads();
  if (tid < 32)
    sm.rowred[tid] = fmaxf(fmaxf(sm.partm[tid][0], sm.partm[tid][1]),
                           fmaxf(sm.partm[tid][2], sm.partm[tid][3]));
  __syncthreads();
  float Mx[4];
#pragma unroll
  for (int rr = 0; rr < 4; ++rr) Mx[rr] = sm.rowred[rbase + rr];
  {
    float ps[4] = {0.f, 0.f, 0.f, 0.f};
#pragma unroll
    for (int i = 0; i < 7; ++i) {
      const int jt = wg + 4 * i;
      if (jt >= 25) continue;
      const int t = jt * 16 + lrow;
      const bool ok = t < len;
#pragma unroll
      for (int rr = 0; rr < 4; ++rr) {
        float e = ok ? __expf(acc[i][rr] - Mx[rr]) : 0.f;
        acc[i][rr] = e;
        ps[rr] += e;
      }
    }
#pragma unroll
    for (int d = 1; d < 16; d <<= 1) {
#pragma unroll
      for (int rr = 0; rr < 4; ++rr) ps[rr] += __shfl_xor(ps[rr], d);
    }
    if (lrow == 0) {
#pragma unroll
      for (int rr = 0; rr < 4; ++rr) sm.parts[rbase + rr][wg] = ps[rr];
    }
  }
  __syncthreads();
  if (tid < 32)
    sm.rowred[tid] = sm.parts[tid][0] + sm.parts[tid][1] + sm.parts[tid][2] + sm.parts[tid][3];
  __syncthreads();
  {
    float inv[4];
#pragma unroll
    for (int rr = 0; rr < 4; ++rr) inv[rr] = 1.f / sm.rowred[rbase + rr];
#pragma unroll
    for (int i = 0; i < 7; ++i) {
      const int jt = wg + 4 * i;
      if (jt >= 25) continue;
      const int t = jt * 16 + lrow;
#pragma unroll
      for (int rr = 0; rr < 4; ++rr) {
        const int row = rbase + rr;
        const float p = acc[i][rr] * inv[rr];
        sm.P[row * PLD + t] = f2bfn(p);
        if (row < 30) attnB[((size_t)s * M + row * B + b) * T + t] = p;
      }
    }
  }
  __syncthreads();

  f32x4 acc2[7] = {};
  {
    const u16* bBase = encT + (size_t)b * 400 * TPAD + c16 * 8;
    const u16* aP = sm.P + (mt * 16 + lrow) * PLD + c16 * 8;
    for (int kk = 0; kk < 13; ++kk) {
      bfrag ap = *(const bfrag*)(aP + kk * 32);
#pragma unroll
      for (int i = 0; i < 7; ++i) {
        const int jk = wg + 4 * i;
        if (jk < 25) {
          bfrag bv = *(const bfrag*)(bBase + (size_t)(jk * 16 + lrow) * TPAD + kk * 32);
          acc2[i] = __builtin_amdgcn_mfma_f32_16x16x32_bf16(ap, bv, acc2[i], 0, 0, 0);
        }
      }
    }
  }
  {
    float pw[4] = {0.f, 0.f, 0.f, 0.f};
    float pg0[4] = {0.f, 0.f, 0.f, 0.f};
    float pg1[4] = {0.f, 0.f, 0.f, 0.f};
    float pg2[4] = {0.f, 0.f, 0.f, 0.f};
    const bool do_g = (s == 0);
#pragma unroll
    for (int i = 0; i < 7; ++i) {
      const int jk = wg + 4 * i;
      if (jk >= 25) continue;
      const int k = jk * 16 + lrow;
      const float wr = Wr[H + k];
      float w0 = 0.f, w1 = 0.f, w2 = 0.f;
      if (do_g) { w0 = Wg[k]; w1 = Wg[H + k]; w2 = Wg[2 * H + k]; }
#pragma unroll
      for (int rr = 0; rr < 4; ++rr) {
        const float v = acc2[i][rr];
        pw[rr] = fmaf(v, wr, pw[rr]);
        if (do_g) {
          pg0[rr] = fmaf(v, w0, pg0[rr]);
          pg1[rr] = fmaf(v, w1, pg1[rr]);
          pg2[rr] = fmaf(v, w2, pg2[rr]);
        }
      }
    }
#pragma unroll
    for (int d = 1; d < 16; d <<= 1) {
#pragma unroll
      for (int rr = 0; rr < 4; ++rr) {
        pw[rr] += __shfl_xor(pw[rr], d);
        pg0[rr] += __shfl_xor(pg0[rr], d);
        pg1[rr] += __shfl_xor(pg1[rr], d);
        pg2[rr] += __shfl_xor(pg2[rr], d);
      }
    }
    if (lrow == 0) {
#pragma unroll
      for (int rr = 0; rr < 4; ++rr) {
        sm.part2[rbase + rr][wg][0] = pw[rr];
        sm.part2[rbase + rr][wg][1] = pg0[rr];
        sm.part2[rbase + rr][wg][2] = pg1[rr];
        sm.part2[rbase + rr][wg][3] = pg2[rr];
      }
    }
  }
  __syncthreads();

  if (tid < 480) {
    const int row = tid >> 4;
    const int l16 = tid & 15;
    const int m = row * B + b;
    const float* hF = hallF + ((size_t)s * M + m) * H;
    const float* dF = dec + ((size_t)s * M + m) * H;
    float p = 0.f;
    for (int j = 0; j < 25; ++j) {
      const int k = l16 + 16 * j;
      p += hF[k] * Wr[k] + dF[k] * Wr[2 * H + k];
    }
#pragma unroll
    for (int d = 1; d < 16; d <<= 1) p += __shfl_xor(p, d);
    if (l16 == 0) {
      float cw = sm.part2[row][0][0] + sm.part2[row][1][0] +
                 sm.part2[row][2][0] + sm.part2[row][3][0];
      pgenB[s * M + m] = sigm(p + cw + br[0]);
    }
    if (s == 0 && l16 < NG) {
      float gv = sm.part2[row][0][1 + l16] + sm.part2[row][1][1 + l16] +
                 sm.part2[row][2][1 + l16] + sm.part2[row][3][1 + l16];
      out[PTS + (long long)m * NG + l16] = gv + bg[l16];
    }
  }
}

// ---------------- k_merge: row-sum from ebuf, scale, write, scatter ----------------
__global__ __launch_bounds__(512) void k_merge(
    const u16* __restrict__ ebuf, const float* __restrict__ pgenB,
    const float* __restrict__ attnB, const int* __restrict__ story,
    float* __restrict__ out)
{
  const int bxi = blockIdx.x;
  const int s = bxi / M, m = bxi % M, b = m % B;
  const size_t R = (size_t)s * MP + m;
  const int tid = threadIdx.x;
  const int wave = tid >> 6, lane = tid & 63;
  __shared__ float red8[8];
  const u16* erow = ebuf + R * VP;
  bfrag ch[6];
  float sum = 0.f;
#pragma unroll
  for (int j = 0; j < 6; ++j) {
    const int c = j * 512 + tid;
    if (c < VP / 8) {
      ch[j] = *(const bfrag*)(erow + (size_t)c * 8);
#pragma unroll
      for (int e = 0; e < 8; ++e) sum += bf2f((u16)ch[j][e]);
    }
  }
#pragma unroll
  for (int off = 32; off; off >>= 1) sum += __shfl_xor(sum, off);
  if (lane == 0) red8[wave] = sum;
  __syncthreads();
  float Sv = 0.f;
#pragma unroll
  for (int j = 0; j < 8; ++j) Sv += red8[j];
  const float pg = pgenB[s * M + m];
  const float scale = pg / Sv;
  float* orow = out + ((size_t)m * STEPS + s) * V;
#pragma unroll
  for (int j = 0; j < 6; ++j) {
    const int c = j * 512 + tid;
    if (c < V / 8) {
      f32x4 w0, w1;
#pragma unroll
      for (int e = 0; e < 4; ++e) {
        w0[e] = bf2f((u16)ch[j][e]) * scale;
        w1[e] = bf2f((u16)ch[j][4 + e]) * scale;
      }
      *(f32x4*)(orow + (size_t)c * 8) = w0;
      *(f32x4*)(orow + (size_t)c * 8 + 4) = w1;
    }
  }
  __syncthreads();
  const float om = 1.f - pg;
  for (int t = tid; t < T; t += 512) {
    float a = attnB[((size_t)s * M + m) * T + t];
    if (a != 0.f) atomicAdd(orow + story[b * T + t], om * a);
  }
}

// ---------------- launch ----------------

extern "C" void kernel_launch(void* const* d_in, const int* in_sizes, int n_in,
                              void* d_out, int out_size, void* d_ws, size_t ws_size,
                              hipStream_t stream) {
  (void)in_sizes; (void)n_in; (void)out_size; (void)ws_size;
  const float* emb  = (const float*)d_in[0];
  const float* Wih  = (const float*)d_in[1];
  const float* Whh  = (const float*)d_in[2];
  const float* bih  = (const float*)d_in[3];
  const float* bhh  = (const float*)d_in[4];
  const float* Wr   = (const float*)d_in[5];
  const float* br   = (const float*)d_in[6];
  const float* Wg   = (const float*)d_in[7];
  const float* bg   = (const float*)d_in[8];
  const float* semb = (const float*)d_in[9];
  const float* ehid = (const float*)d_in[10];
  const float* enc  = (const float*)d_in[11];
  const int*   lens = (const int*)d_in[12];
  const int*   story= (const int*)d_in[13];
  const int*   tgt  = (const int*)d_in[14];
  float* out = (float*)d_out;

  char* w = (char*)d_ws;
  size_t off = 0;
  auto alloc = [&](size_t n) -> void* {
    void* p = w + off;
    off = (off + n + 255) & ~(size_t)255;
    return p;
  };
  u16* ebf    = (u16*)alloc((size_t)VP * KP * 2);
  u16* wihH   = (u16*)alloc((size_t)NWP * KP * 2);
  u16* wihL   = (u16*)alloc((size_t)NWP * KP * 2);
  u16* whhH   = (u16*)alloc((size_t)NWP * KP * 2);
  u16* whhL   = (u16*)alloc((size_t)NWP * KP * 2);
  u16* decH   = (u16*)alloc((size_t)STEPS * MP * KP * 2);
  u16* decL   = (u16*)alloc((size_t)STEPS * MP * KP * 2);
  float* dec  = (float*)alloc((size_t)STEPS * M * H * 4);
  float* h0F  = (float*)alloc((size_t)M * H * 4);
  u16* h0H    = (u16*)alloc((size_t)MP * KP * 2);
  u16* h0L    = (u16*)alloc((size_t)MP * KP * 2);
  u16* hAllH  = (u16*)alloc((size_t)MR * KP * 2);
  u16* hAllL  = (u16*)alloc((size_t)MR * KP * 2);
  float* hallF= (float*)alloc((size_t)STEPS * M * H * 4);
  float* gi   = (float*)alloc((size_t)MR * H3 * 4);
  float* gh   = (float*)alloc((size_t)M * H3 * 4);
  float* attnB= (float*)alloc((size_t)STEPS * M * T * 4);
  float* pgenB= (float*)alloc((size_t)STEPS * M * 4);
  u16* ebuf   = (u16*)alloc((size_t)MR * VP * 2);
  u16* encbK  = (u16*)alloc((size_t)B * 400 * TPAD * 2);
  u16* encT   = (u16*)alloc((size_t)B * 400 * TPAD * 2);

  k_init<<<N_INIT, 256, 0, stream>>>(emb, enc, Wih, Whh, semb, ehid, tgt,
      ebf, encbK, encT, wihH, wihL, whhH, whhL, dec, decH, decL,
      h0F, h0H, h0L, hAllH, hAllL, ebuf);
  // all-steps gi = dec @ Wih^T + bih
  k_gemm64s<<<dim3(NCT, MR / 64), 256, 0, stream>>>(
      decH, decL, wihH, wihL, bih, gi, MR, H3, H3);

  // step 0 spine (no vocab to overlap yet)
  k_gemm64s<<<dim3(NCT, (M + 63) / 64), 256, 0, stream>>>(
      h0H, h0L, whhH, whhL, bhh, gh, M, H3, H3);
  k_cell<<<(M * H + 511) / 512, 512, 0, stream>>>(
      gi, gh, h0F, hallF, hAllH, hAllL);

  // steps 1..7: vocab(s-1) ∥ gh(s) in one launch, then cell(s)
  for (int s = 1; s < STEPS; ++s) {
    k_bigv<<<NVB_S + NGH, 512, 0, stream>>>(
        hAllH + (size_t)(s - 1) * MP * KP, hAllL + (size_t)(s - 1) * MP * KP,
        ebf, ebuf, (long long)(s - 1) * MP, whhH, whhL, bhh, gh);
    k_cell<<<(M * H + 511) / 512, 512, 0, stream>>>(
        gi + (size_t)s * MP * H3, gh, hallF + (size_t)(s - 1) * M * H,
        hallF + (size_t)s * M * H,
        hAllH + (size_t)s * MP * KP, hAllL + (size_t)s * MP * KP);
  }
  // tail: vocab(7) alone (grid has no gh blocks)
  k_bigv<<<NVB_S, 512, 0, stream>>>(
      hAllH + (size_t)7 * MP * KP, hAllL + (size_t)7 * MP * KP,
      ebf, ebuf, (long long)7 * MP, whhH, whhL, bhh, gh);

  // batched parallel phase
  k_attn<<<STEPS * B, 512, 0, stream>>>(hAllH, hAllL, hallF, encbK, encT, lens,
                                        dec, Wr, br, Wg, bg, attnB, pgenB, out);
  k_merge<<<STEPS * M, 512, 0, stream>>>(ebuf, pgenB, attnB, story, out);
}